// Round 1
// 572.751 us; speedup vs baseline: 1.0442x; 1.0442x over previous
//
#include <hip/hip_runtime.h>

// RWKV7 attention block, MI355X/gfx950.
// B=1, T=1024, C=2048, H=32, N=64. All inputs/outputs f32.
// Big GEMMs: f16 MFMA 16x16x32, double-buffered global_load_lds(16B) staging.
// LoRA stage-1: MFMA split-K, deterministic per-split partials.
// WKV scan v6: 8 blocks/head, dbuf async staging, software-pipelined LDS->reg
// reads, DPP reductions. Output reduction DEFERRED to chunk end: per-step the
// wave only keeps the per-lane partial (4 fma, off the carried chain); the 16
// REDUCE16 butterflies run as independent chains at chunk end so their DPP
// latencies pipeline, and the exec-masked store region is 1x/chunk not 16x.

#define T_ 1024
#define C_ 2048
#define H_ 32
#define N_ 64

using half8  = __attribute__((ext_vector_type(8))) _Float16;  // 8 f16 (4 VGPRs)
using half4  = __attribute__((ext_vector_type(4))) _Float16;  // 8 B
using floatx4 = __attribute__((ext_vector_type(4))) float;    // 4 f32 acc

// DPP xor-add within 16-lane rows: quad_perm(0xB1)=xor1, quad_perm(0x4E)=xor2,
// row_half_mirror(0x141)=xor4, row_mirror(0x140)=xor8.
#define DPP_ADD(v, ctrl) \
    ((v) + __int_as_float(__builtin_amdgcn_update_dpp( \
        0, __float_as_int(v), (ctrl), 0xf, 0xf, true)))
#define REDUCE16(v) do { \
    v = DPP_ADD(v, 0xB1); v = DPP_ADD(v, 0x4E); \
    v = DPP_ADD(v, 0x141); v = DPP_ADD(v, 0x140); } while (0)

// async 16B global->LDS (direct-to-LDS DMA; HW dest = wave base + lane*16,
// all call sites construct per-lane lds ptrs matching exactly that layout)
__device__ __forceinline__ void async_cp16(const void* g, void* l) {
    __builtin_amdgcn_global_load_lds(
        (const __attribute__((address_space(1))) void*)g,
        (__attribute__((address_space(3))) void*)l, 16, 0, 0);
}

// ---------------------------------------------------------------------------
// Transpose + convert big weights: W[k][n] f32 -> WT[n][k] f16
// ---------------------------------------------------------------------------
__global__ __launch_bounds__(256) void k_tr(
    const float* __restrict__ W0, const float* __restrict__ W1,
    const float* __restrict__ W2, const float* __restrict__ W3,
    _Float16* __restrict__ D0, _Float16* __restrict__ D1,
    _Float16* __restrict__ D2, _Float16* __restrict__ D3)
{
    const int z = blockIdx.z;
    const float* S = (z == 0) ? W0 : (z == 1) ? W1 : (z == 2) ? W2 : W3;
    _Float16* D = (z == 0) ? D0 : (z == 1) ? D1 : (z == 2) ? D2 : D3;
    const int nb = blockIdx.x * 64, kb = blockIdx.y * 64;
    __shared__ __align__(16) float tile[64][65];
    const int tr = threadIdx.x >> 4, tc4 = (threadIdx.x & 15) * 4;
#pragma unroll
    for (int p = 0; p < 4; ++p) {
        int row = p * 16 + tr;
        float4 v = *(const float4*)&S[(size_t)(kb + row) * C_ + nb + tc4];
        tile[row][tc4 + 0] = v.x; tile[row][tc4 + 1] = v.y;
        tile[row][tc4 + 2] = v.z; tile[row][tc4 + 3] = v.w;
    }
    __syncthreads();
#pragma unroll
    for (int p = 0; p < 4; ++p) {
        int n = p * 16 + tr;
        half4 u;
        u[0] = (_Float16)tile[tc4 + 0][n];
        u[1] = (_Float16)tile[tc4 + 1][n];
        u[2] = (_Float16)tile[tc4 + 2][n];
        u[3] = (_Float16)tile[tc4 + 3][n];
        *(half4*)&D[(size_t)(nb + n) * C_ + kb + tc4] = u;
    }
}

// ---------------------------------------------------------------------------
// Pack+transpose LoRA weights to f16 WT[n][k].
// z=0: WT_m [128][2048] <- maa_w1[2048,128]
// z=1: WT_l [256][2048] <- gate(128) | decay(64) | aaa(16) | ma(16) | kkk(16) | mk(16)
// ---------------------------------------------------------------------------
__global__ __launch_bounds__(256) void k_trW(
    const float* __restrict__ maa_w1, const float* __restrict__ gate_w1,
    const float* __restrict__ decay_w1, const float* __restrict__ aaa_w1,
    const float* __restrict__ ma_w1, const float* __restrict__ kkk_w1,
    const float* __restrict__ mk_w1,
    _Float16* __restrict__ WTm, _Float16* __restrict__ WTl)
{
    const int z = blockIdx.z;
    const int k = blockIdx.x * 256 + threadIdx.x;   // 0..2047
    const int n = blockIdx.y;
    if (z == 0 && n >= 128) return;
    const float* src; int stride, col;
    _Float16* dst;
    if (z == 0) { src = maa_w1; stride = 128; col = n; dst = WTm; }
    else {
        dst = WTl;
        if (n < 128)      { src = gate_w1;  stride = 128; col = n; }
        else if (n < 192) { src = decay_w1; stride = 64;  col = n - 128; }
        else if (n < 208) { src = aaa_w1;   stride = 16;  col = n - 192; }
        else if (n < 224) { src = ma_w1;    stride = 16;  col = n - 208; }
        else if (n < 240) { src = kkk_w1;   stride = 16;  col = n - 224; }
        else              { src = mk_w1;    stride = 16;  col = n - 240; }
    }
    dst[(size_t)n * C_ + k] = (_Float16)src[(size_t)k * stride + col];
}

// ---------------------------------------------------------------------------
// xxxH = f16( x + (x_prev - x) * maa_x )
// ---------------------------------------------------------------------------
__global__ __launch_bounds__(256) void k_prep(
    const float* __restrict__ X, const float* __restrict__ maa_x,
    _Float16* __restrict__ xxxH)
{
    const size_t idx = (size_t)blockIdx.x * 256 + threadIdx.x;
    const int c = (int)(idx & (C_ - 1));
    float cur = X[idx];
    float prev = (idx >= C_) ? X[idx - C_] : 0.0f;
    xxxH[idx] = (_Float16)(cur + (prev - cur) * maa_x[c]);
}

// ---------------------------------------------------------------------------
// LoRA MFMA GEMM, split-K -> per-split partials (deterministic; no atomics).
// BM=64, BN=32, BK=32, ksplit=4.
// which=0: m1p[ks][1024][128] = xxxH @ WTm^T (4 n-tiles)
// which=1: l2p[ks][1024][256], A per n-tile: 0-3 xrg | 4-6 xwa | 7 xk
// ---------------------------------------------------------------------------
__global__ __launch_bounds__(256) void k_lora(
    int which,
    const _Float16* __restrict__ Axxx, const _Float16* __restrict__ Axrg,
    const _Float16* __restrict__ Axwa, const _Float16* __restrict__ Axk,
    const _Float16* __restrict__ WTm, const _Float16* __restrict__ WTl,
    float* __restrict__ m1p, float* __restrict__ l2p)
{
    const int mt = blockIdx.x;      // 16 tiles of 64 rows
    const int nt = blockIdx.y;      // tiles of 32 cols
    const int ks = blockIdx.z;      // 4 K-chunks of 512
    const _Float16* A; const _Float16* BT; float* O; int ostride;
    if (which == 0) { A = Axxx; BT = WTm; O = m1p; ostride = 128; }
    else {
        BT = WTl; O = l2p; ostride = 256;
        A = (nt < 4) ? Axrg : (nt < 7) ? Axwa : Axk;
    }
    O += (size_t)ks * T_ * ostride;
    const int m0 = mt * 64, n0 = nt * 32, k0 = ks * 512;
    const int tid = threadIdx.x;
    __shared__ __align__(16) _Float16 As[64 * 40];
    __shared__ __align__(16) _Float16 Bs[32 * 40];
    const int lane = tid & 63, wv = tid >> 6;
    const int r16 = lane & 15, q = lane >> 4;

    floatx4 acc[2];
    { floatx4 zv = {0.f, 0.f, 0.f, 0.f}; acc[0] = zv; acc[1] = zv; }

    const int arow = tid >> 2, ac8 = (tid & 3) * 8;
    const _Float16* ag = A + (size_t)(m0 + arow) * C_ + k0 + ac8;
    const _Float16* bg = BT + (size_t)(n0 + (tid >> 2)) * C_ + k0 + ac8;

    for (int kc = 0; kc < 512; kc += 32) {
        half8 av = *(const half8*)(ag + kc);
        half8 bv;
        if (tid < 128) bv = *(const half8*)(bg + kc);
        *(half8*)&As[arow * 40 + ac8] = av;
        if (tid < 128) *(half8*)&Bs[(tid >> 2) * 40 + ac8] = bv;
        __syncthreads();
        half8 af = *(const half8*)&As[(wv * 16 + r16) * 40 + q * 8];
        half8 b0 = *(const half8*)&Bs[(r16) * 40 + q * 8];
        half8 b1 = *(const half8*)&Bs[(16 + r16) * 40 + q * 8];
        acc[0] = __builtin_amdgcn_mfma_f32_16x16x32_f16(af, b0, acc[0], 0, 0, 0);
        acc[1] = __builtin_amdgcn_mfma_f32_16x16x32_f16(af, b1, acc[1], 0, 0, 0);
        __syncthreads();
    }
#pragma unroll
    for (int j = 0; j < 2; ++j)
#pragma unroll
        for (int e = 0; e < 4; ++e) {
            int row = m0 + wv * 16 + q * 4 + e;
            int col = n0 + j * 16 + r16;
            O[(size_t)row * ostride + col] = acc[j][e];
        }
}

// ---------------------------------------------------------------------------
// xmix: m1 = sum_ks(m1p), tanh; mix = einsum(m1[T,4,32], maa_w2[4,32,C]);
// emit f16 GEMM operands xrgH/xwaH/xkH/xvH.
// ---------------------------------------------------------------------------
__global__ __launch_bounds__(256) void k_xmix(
    const float* __restrict__ X, const float* __restrict__ m1p,
    const float* __restrict__ w2,
    const float* __restrict__ mrg, const float* __restrict__ mwa,
    const float* __restrict__ mk, const float* __restrict__ mv,
    _Float16* __restrict__ xrgH, _Float16* __restrict__ xwaH,
    _Float16* __restrict__ xkH, _Float16* __restrict__ xvH)
{
    const int tid = threadIdx.x;
    const int c = blockIdx.x * 256 + tid;
    const int t0 = blockIdx.y * 16;
    const size_t P = (size_t)T_ * 128;
    __shared__ __align__(16) float m1s[16][128];
#pragma unroll
    for (int p = 0; p < 2; ++p) {
        int id = tid + p * 256;
        int r = id >> 5, c4 = (id & 31) * 4;
        size_t off = (size_t)(t0 + r) * 128 + c4;
        float4 v0 = *(const float4*)&m1p[off];
        float4 v1 = *(const float4*)&m1p[P + off];
        float4 v2 = *(const float4*)&m1p[2 * P + off];
        float4 v3 = *(const float4*)&m1p[3 * P + off];
        float4 v;
        v.x = tanhf(((v0.x + v1.x) + v2.x) + v3.x);
        v.y = tanhf(((v0.y + v1.y) + v2.y) + v3.y);
        v.z = tanhf(((v0.z + v1.z) + v2.z) + v3.z);
        v.w = tanhf(((v0.w + v1.w) + v2.w) + v3.w);
        *(float4*)&m1s[r][c4] = v;
    }
    __syncthreads();
    float a0[16], a1[16], a2[16], a3[16];
#pragma unroll
    for (int t = 0; t < 16; ++t) { a0[t] = 0.f; a1[t] = 0.f; a2[t] = 0.f; a3[t] = 0.f; }
    for (int d = 0; d < 32; ++d) {
        float w0 = w2[(size_t)(0 * 32 + d) * C_ + c];
        float w1 = w2[(size_t)(1 * 32 + d) * C_ + c];
        float w2v = w2[(size_t)(2 * 32 + d) * C_ + c];
        float w3 = w2[(size_t)(3 * 32 + d) * C_ + c];
#pragma unroll
        for (int t = 0; t < 16; ++t) {
            a0[t] = fmaf(m1s[t][d],      w0,  a0[t]);
            a1[t] = fmaf(m1s[t][32 + d], w1,  a1[t]);
            a2[t] = fmaf(m1s[t][64 + d], w2v, a2[t]);
            a3[t] = fmaf(m1s[t][96 + d], w3,  a3[t]);
        }
    }
    float vrg = mrg[c], vwa = mwa[c], vmk = mk[c], vmv = mv[c];
    float prev = (t0 > 0) ? X[(size_t)(t0 - 1) * C_ + c] : 0.0f;
    for (int t = 0; t < 16; ++t) {
        size_t idx = (size_t)(t0 + t) * C_ + c;
        float cur = X[idx];
        float dx = prev - cur;
        xrgH[idx] = (_Float16)(cur + dx * (vrg + a0[t]));
        xwaH[idx] = (_Float16)(cur + dx * (vwa + a1[t]));
        xkH[idx]  = (_Float16)(cur + dx * (vmk + a2[t]));
        xvH[idx]  = (_Float16)(cur + dx * (vmv + a3[t]));
        prev = cur;
    }
}

// ---------------------------------------------------------------------------
// f16 MFMA GEMM: C[1024,2048] = A(f16) @ W via WT[n][k] f16.
// BM=BN=128, BK=32, 256 thr (4 waves 2x2), 4x4 16x16x32 tiles/wave.
// Double-buffered global_load_lds staging.
// ---------------------------------------------------------------------------
__global__ __launch_bounds__(256) void k_gemm(
    const _Float16* __restrict__ A0, const _Float16* __restrict__ B0, float* __restrict__ C0,
    const _Float16* __restrict__ A1, const _Float16* __restrict__ B1, float* __restrict__ C1,
    const _Float16* __restrict__ A2, const _Float16* __restrict__ B2, float* __restrict__ C2)
{
    const int z = blockIdx.z;
    const _Float16* A = (z == 0) ? A0 : (z == 1) ? A1 : A2;
    const _Float16* Bt = (z == 0) ? B0 : (z == 1) ? B1 : B2;
    float* C = (z == 0) ? C0 : (z == 1) ? C1 : C2;
    const int mtile = blockIdx.y * 128;
    const int ntile = blockIdx.x * 128;
    const int tid = threadIdx.x;
    __shared__ __align__(16) _Float16 As[2][128 * 32];  // unpadded (async layout)
    __shared__ __align__(16) _Float16 Bs[2][128 * 32];
    const int lane = tid & 63;
    const int wvid = tid >> 6;
    const int wm = wvid >> 1, wn = wvid & 1;
    const int r16 = lane & 15, q = lane >> 4;

    floatx4 acc[4][4];
#pragma unroll
    for (int i = 0; i < 4; ++i)
#pragma unroll
        for (int j = 0; j < 4; ++j) { floatx4 zv = {0.f, 0.f, 0.f, 0.f}; acc[i][j] = zv; }

    const int srow = tid >> 2, sq = tid & 3;
    const _Float16* agA = A + (size_t)(mtile + srow) * C_ + sq * 8;
    const _Float16* agB = Bt + (size_t)(ntile + srow) * C_ + sq * 8;
    const int ldso = srow * 32 + sq * 8;
    const size_t rowoff = (size_t)64 * C_;

    async_cp16(agA, &As[0][ldso]);
    async_cp16(agA + rowoff, &As[0][ldso + 64 * 32]);
    async_cp16(agB, &Bs[0][ldso]);
    async_cp16(agB + rowoff, &Bs[0][ldso + 64 * 32]);

    for (int kc = 0; kc < C_; kc += 32) {
        const int p = (kc >> 5) & 1;
        __syncthreads();                      // buf p ready (drains copies)
        if (kc + 32 < C_) {                   // prefetch k+1 into buf p^1
            async_cp16(agA + kc + 32, &As[p ^ 1][ldso]);
            async_cp16(agA + kc + 32 + rowoff, &As[p ^ 1][ldso + 64 * 32]);
            async_cp16(agB + kc + 32, &Bs[p ^ 1][ldso]);
            async_cp16(agB + kc + 32 + rowoff, &Bs[p ^ 1][ldso + 64 * 32]);
        }
        half8 af[4], bf[4];
#pragma unroll
        for (int i = 0; i < 4; ++i)
            af[i] = *(const half8*)&As[p][(wm * 64 + i * 16 + r16) * 32 + q * 8];
#pragma unroll
        for (int j = 0; j < 4; ++j)
            bf[j] = *(const half8*)&Bs[p][(wn * 64 + j * 16 + r16) * 32 + q * 8];
#pragma unroll
        for (int i = 0; i < 4; ++i)
#pragma unroll
            for (int j = 0; j < 4; ++j)
                acc[i][j] = __builtin_amdgcn_mfma_f32_16x16x32_f16(af[i], bf[j], acc[i][j], 0, 0, 0);
    }
    // C/D layout: col = lane&15, row = (lane>>4)*4 + reg
#pragma unroll
    for (int i = 0; i < 4; ++i)
#pragma unroll
        for (int j = 0; j < 4; ++j)
#pragma unroll
            for (int e = 0; e < 4; ++e) {
                int row = mtile + wm * 64 + i * 16 + q * 4 + e;
                int col = ntile + wn * 64 + j * 16 + r16;
                C[(size_t)row * C_ + col] = acc[i][j][e];
            }
}

// ---------------------------------------------------------------------------
// Fused stage-2: dec=exp(w), kk (normalized), b = kk*a, k_final.
// l2p partials [4][T][256]: cols 128-191 decay(tanh) | 192-207 aaa |
// 208-223 ma | 224-239 kkk(tanh) | 240-255 mk. Fixed-order reduce.
// ---------------------------------------------------------------------------
__global__ __launch_bounds__(256) void k_fuse(
    const float* __restrict__ l2p,
    float* __restrict__ K0,
    const float* __restrict__ decay_w2, const float* __restrict__ aaa_w2,
    const float* __restrict__ ma_w2, const float* __restrict__ kkk_w2,
    const float* __restrict__ mk_w2,
    const float* __restrict__ tdecay, const float* __restrict__ aaaaa,
    const float* __restrict__ misc_a, const float* __restrict__ misc_k,
    float* __restrict__ Dout, float* __restrict__ KKout, float* __restrict__ Bout)
{
    const int tid = threadIdx.x;
    const int c = blockIdx.x * 256 + tid;
    const int t0 = blockIdx.y * 16;
    const size_t P = (size_t)T_ * 256;
    __shared__ __align__(16) float wsS[16][96];   // decay64 | aaa16 | ma16
    __shared__ __align__(16) float ksS[16][32];   // kkk16 | mk16
    for (int id = tid; id < 16 * 24; id += 256) {
        int r = id / 24, c4 = (id % 24) * 4;
        size_t off = (size_t)(t0 + r) * 256 + 128 + c4;
        float4 v0 = *(const float4*)&l2p[off];
        float4 v1 = *(const float4*)&l2p[P + off];
        float4 v2 = *(const float4*)&l2p[2 * P + off];
        float4 v3 = *(const float4*)&l2p[3 * P + off];
        float4 v;
        v.x = ((v0.x + v1.x) + v2.x) + v3.x;
        v.y = ((v0.y + v1.y) + v2.y) + v3.y;
        v.z = ((v0.z + v1.z) + v2.z) + v3.z;
        v.w = ((v0.w + v1.w) + v2.w) + v3.w;
        if (c4 < 64) { v.x = tanhf(v.x); v.y = tanhf(v.y); v.z = tanhf(v.z); v.w = tanhf(v.w); }
        *(float4*)&wsS[r][c4] = v;
    }
    for (int id = tid; id < 16 * 8; id += 256) {
        int r = id / 8, c4 = (id % 8) * 4;
        size_t off = (size_t)(t0 + r) * 256 + 224 + c4;
        float4 v0 = *(const float4*)&l2p[off];
        float4 v1 = *(const float4*)&l2p[P + off];
        float4 v2 = *(const float4*)&l2p[2 * P + off];
        float4 v3 = *(const float4*)&l2p[3 * P + off];
        float4 v;
        v.x = ((v0.x + v1.x) + v2.x) + v3.x;
        v.y = ((v0.y + v1.y) + v2.y) + v3.y;
        v.z = ((v0.z + v1.z) + v2.z) + v3.z;
        v.w = ((v0.w + v1.w) + v2.w) + v3.w;
        if (c4 < 16) { v.x = tanhf(v.x); v.y = tanhf(v.y); v.z = tanhf(v.z); v.w = tanhf(v.w); }
        *(float4*)&ksS[r][c4] = v;
    }
    __syncthreads();
    float accW[16], accA[16], accMA[16], accKK[16], accMK[16];
#pragma unroll
    for (int r = 0; r < 16; ++r) { accW[r] = 0.f; accA[r] = 0.f; accMA[r] = 0.f; accKK[r] = 0.f; accMK[r] = 0.f; }
    for (int j = 0; j < 64; ++j) {
        float w = decay_w2[(size_t)j * C_ + c];
#pragma unroll
        for (int r = 0; r < 16; ++r) accW[r] = fmaf(wsS[r][j], w, accW[r]);
    }
    for (int j = 0; j < 16; ++j) {
        float wa = aaa_w2[(size_t)j * C_ + c];
        float wm = ma_w2[(size_t)j * C_ + c];
        float wk = kkk_w2[(size_t)j * C_ + c];
        float wq = mk_w2[(size_t)j * C_ + c];
#pragma unroll
        for (int r = 0; r < 16; ++r) {
            accA[r]  = fmaf(wsS[r][64 + j], wa, accA[r]);
            accMA[r] = fmaf(wsS[r][80 + j], wm, accMA[r]);
            accKK[r] = fmaf(ksS[r][j],      wk, accKK[r]);
            accMK[r] = fmaf(ksS[r][16 + j], wq, accMK[r]);
        }
    }
    float td = tdecay[c], aa = aaaaa[c], mia = misc_a[c], mik = misc_k[c];
    for (int r = 0; r < 16; ++r) {
        size_t idx = (size_t)(t0 + r) * C_ + c;
        float wraw = td + accW[r];
        float w = -logf(1.0f + __expf(-wraw)) - 0.5f;   // -softplus(-x) - 0.5
        float a  = 1.0f / (1.0f + __expf(-(aa  + accA[r])));
        float mav = 1.0f / (1.0f + __expf(-(mia + accMA[r])));
        float mkv = 1.0f / (1.0f + __expf(-(mik + accMK[r])));
        float k0 = K0[idx];
        float kkun = k0 + accKK[r];
        float ss = kkun * kkun;
        REDUCE16(ss);
        ss += __shfl_xor(ss, 16, 64);
        ss += __shfl_xor(ss, 32, 64);
        float kn = kkun * (1.0f / fmaxf(sqrtf(ss), 1e-12f));
        Dout[idx]  = __expf(w);                 // dec, precomputed for the scan
        KKout[idx] = kn;
        Bout[idx]  = kn * a;
        K0[idx]    = k0 * (mav + a * (1.0f - mav)) * __expf(fminf(w * mkv, 0.0f));
    }
}

// ---------------------------------------------------------------------------
// WKV7 scan v6: 8 blocks/head (8 rows each) -> 256 blocks, 128 thr (2 waves).
// Dbuf async LDS staging + software-pipelined LDS->reg reads (step tt+1
// loaded while computing tt). Wave = 4 row-slots x 16 j-groups.
// Per-step loop-carried chain: sa tree-dot (depth 3) -> REDUCE16 (4 DPP hops)
// -> state fma (depth 2). Output kept as per-lane partial po[tt]; the 16
// butterflies + exec-masked stores run once per chunk (independent chains
// pipeline; no per-step exec-region serialization).
// ---------------------------------------------------------------------------
__global__ __launch_bounds__(128) void k_wkv(
    const float* __restrict__ R, const float* __restrict__ DEC,
    const float* __restrict__ K, const float* __restrict__ V,
    const float* __restrict__ KK, const float* __restrict__ Bb,
    float* __restrict__ Y)
{
    const int tid = threadIdx.x;
    const int h = blockIdx.x >> 3;
    const int rg = blockIdx.x & 7;
    const int c0 = h * 64;
    const int wv = tid >> 6, lane = tid & 63;
    const int rowslot = lane >> 4;                     // 0..3
    const int lrow = wv * 4 + rowslot;                 // block-local row 0..7
    const int irow = rg * 8 + lrow;                    // row within head
    const int jg = lane & 15, j4 = jg * 4;

    // [buf][step][64] j-arrays + [buf][step][8] v — all async-copy layouts:
    // slot s (=staging thread or thread+128) maps to byte offset s*16.
    __shared__ __align__(16) float rS[2][16][64], dS[2][16][64], kS[2][16][64],
                                   aS[2][16][64], bS[2][16][64];
    __shared__ __align__(16) float vS[2][16][8];

    // j-array staging: slots tid and tid+128 -> (step = s>>4, quad = s&15)
    const int s0_step = tid >> 4, s0_q4 = (tid & 15) * 4;
    const int s1_step = (tid + 128) >> 4, s1_q4 = ((tid + 128) & 15) * 4;
    // v staging (threads 0..31): step = tid>>1, quad = tid&1
    const int v_step = tid >> 1, v_q4 = (tid & 1) * 4;

#define WKV_STAGE(buf, tcb) do {                                              \
    size_t g0 = (size_t)((tcb) + s0_step) * C_ + c0 + s0_q4;                  \
    size_t g1 = (size_t)((tcb) + s1_step) * C_ + c0 + s1_q4;                  \
    async_cp16(&R[g0],   &rS[buf][s0_step][s0_q4]);                           \
    async_cp16(&R[g1],   &rS[buf][s1_step][s1_q4]);                           \
    async_cp16(&DEC[g0], &dS[buf][s0_step][s0_q4]);                           \
    async_cp16(&DEC[g1], &dS[buf][s1_step][s1_q4]);                           \
    async_cp16(&K[g0],   &kS[buf][s0_step][s0_q4]);                           \
    async_cp16(&K[g1],   &kS[buf][s1_step][s1_q4]);                           \
    async_cp16(&KK[g0],  &aS[buf][s0_step][s0_q4]);                           \
    async_cp16(&KK[g1],  &aS[buf][s1_step][s1_q4]);                           \
    async_cp16(&Bb[g0],  &bS[buf][s0_step][s0_q4]);                           \
    async_cp16(&Bb[g1],  &bS[buf][s1_step][s1_q4]);                           \
    if (tid < 32)                                                             \
        async_cp16(&V[(size_t)((tcb) + v_step) * C_ + c0 + rg * 8 + v_q4],    \
                   &vS[buf][v_step][v_q4]);                                   \
} while (0)

    WKV_STAGE(0, 0);

    float4 s = make_float4(0.f, 0.f, 0.f, 0.f);

    for (int tc = 0; tc < T_; tc += 16) {
        const int p = (tc >> 4) & 1;
        __syncthreads();                               // buf p ready
        if (tc + 16 < T_) WKV_STAGE(p ^ 1, tc + 16);   // prefetch next chunk

        float po[16];                                  // per-lane out partials

        // software pipeline: load step tt+1 while computing tt
        float4 cr = *(float4*)&rS[p][0][j4];
        float4 cd = *(float4*)&dS[p][0][j4];
        float4 ck = *(float4*)&kS[p][0][j4];
        float4 ca = *(float4*)&aS[p][0][j4];
        float4 cb = *(float4*)&bS[p][0][j4];
        float   cv = vS[p][0][lrow];
#pragma unroll
        for (int tt = 0; tt < 16; ++tt) {
            float4 nr, nd, nk, na, nb; float nv = 0.f;
            if (tt < 15) {
                nr = *(float4*)&rS[p][tt + 1][j4];
                nd = *(float4*)&dS[p][tt + 1][j4];
                nk = *(float4*)&kS[p][tt + 1][j4];
                na = *(float4*)&aS[p][tt + 1][j4];
                nb = *(float4*)&bS[p][tt + 1][j4];
                nv = vS[p][tt + 1][lrow];
            }
            // pairwise tree (depth 3) instead of depth-4 chain
            float d01 = fmaf(s.y, ca.y, s.x * ca.x);
            float d23 = fmaf(s.w, ca.w, s.z * ca.z);
            float sa = -(d01 + d23);
            REDUCE16(sa);
            s.x = fmaf(s.x, cd.x, fmaf(sa, cb.x, cv * ck.x));
            s.y = fmaf(s.y, cd.y, fmaf(sa, cb.y, cv * ck.y));
            s.z = fmaf(s.z, cd.z, fmaf(sa, cb.z, cv * ck.z));
            s.w = fmaf(s.w, cd.w, fmaf(sa, cb.w, cv * ck.w));
            // per-lane partial only — reduction deferred off the carried chain
            po[tt] = fmaf(s.w, cr.w, fmaf(s.z, cr.z, fmaf(s.y, cr.y, s.x * cr.x)));
            cr = nr; cd = nd; ck = nk; ca = na; cb = nb; cv = nv;
        }
        // deferred output reductions: 16 independent DPP butterflies pipeline
#pragma unroll
        for (int tt = 0; tt < 16; ++tt) REDUCE16(po[tt]);
        if (jg == 0) {
#pragma unroll
            for (int tt = 0; tt < 16; ++tt)
                Y[(size_t)(tc + tt) * C_ + c0 + irow] = po[tt];
        }
    }
#undef WKV_STAGE
}

// ---------------------------------------------------------------------------
// GroupNorm + bonus + fused gate, t-tiled (16 t/block so the 128 gw2 loads
// amortize): YG = f16((gn(y) + bonus) * (tanh(l2 sum) @ gate_w2)).
// ---------------------------------------------------------------------------
__global__ __launch_bounds__(256) void k_gn(
    const float* __restrict__ Y, const float* __restrict__ R, const float* __restrict__ K,
    const float* __restrict__ V, const float* __restrict__ l2p,
    const float* __restrict__ gw2,
    const float* __restrict__ faaaa, const float* __restrict__ lnw,
    const float* __restrict__ lnb, _Float16* __restrict__ YG)
{
    const int tid = threadIdx.x;
    const int c = blockIdx.x * 256 + tid;
    const int t0 = blockIdx.y * 16;
    const size_t P = (size_t)T_ * 256;
    __shared__ __align__(16) float gs[16][128];
    for (int id = tid; id < 16 * 128; id += 256) {
        int r = id >> 7, cc = id & 127;
        size_t off = (size_t)(t0 + r) * 256 + cc;
        float v = ((l2p[off] + l2p[P + off]) + l2p[2 * P + off]) + l2p[3 * P + off];
        gs[r][cc] = tanhf(v);
    }
    __syncthreads();
    float gacc[16];
#pragma unroll
    for (int r = 0; r < 16; ++r) gacc[r] = 0.f;
    for (int j = 0; j < 128; ++j) {
        float w = gw2[(size_t)j * C_ + c];
#pragma unroll
        for (int r = 0; r < 16; ++r) gacc[r] = fmaf(gs[r][j], w, gacc[r]);
    }
    float fa = faaaa[c], lw = lnw[c], lb = lnb[c];
    for (int r = 0; r < 16; ++r) {
        const size_t idx = (size_t)(t0 + r) * C_ + c;
        float y = Y[idx];
        float s1 = y, s2 = y * y;
#pragma unroll
        for (int off = 1; off < 64; off <<= 1) {
            s1 += __shfl_xor(s1, off, 64);
            s2 += __shfl_xor(s2, off, 64);
        }
        float mu = s1 * (1.0f / 64.0f);
        float var = s2 * (1.0f / 64.0f) - mu * mu;
        float gn = (y - mu) * rsqrtf(var + 0.00064f) * lw + lb;
        float p = R[idx] * K[idx] * fa;
#pragma unroll
        for (int off = 1; off < 64; off <<= 1) p += __shfl_xor(p, off, 64);
        float y2 = gn + p * V[idx];
        YG[idx] = (_Float16)(y2 * gacc[r]);
    }
}

// ---------------------------------------------------------------------------
extern "C" void kernel_launch(void* const* d_in, const int* in_sizes, int n_in,
                              void* d_out, int out_size, void* d_ws, size_t ws_size,
                              hipStream_t stream)
{
    (void)in_sizes; (void)n_in; (void)out_size; (void)ws_size;
    const float* hidden   = (const float*)d_in[0];
    const float* Wq       = (const float*)d_in[1];
    const float* Wk       = (const float*)d_in[2];
    const float* Wv       = (const float*)d_in[3];
    const float* Wo       = (const float*)d_in[4];
    const float* maa_x    = (const float*)d_in[5];
    const float* maa_rg   = (const float*)d_in[6];
    const float* maa_wa   = (const float*)d_in[7];
    const float* maa_k    = (const float*)d_in[8];
    const float* maa_v    = (const float*)d_in[9];
    const float* maa_w1   = (const float*)d_in[10];
    const float* maa_w2   = (const float*)d_in[11];
    const float* tdecay   = (const float*)d_in[12];
    const float* decay_w1 = (const float*)d_in[13];
    const float* decay_w2 = (const float*)d_in[14];
    const float* aaaaa    = (const float*)d_in[15];
    const float* aaa_w1   = (const float*)d_in[16];
    const float* aaa_w2   = (const float*)d_in[17];
    const float* kkk_w1   = (const float*)d_in[18];
    const float* kkk_w2   = (const float*)d_in[19];
    const float* gate_w1  = (const float*)d_in[20];
    const float* gate_w2  = (const float*)d_in[21];
    const float* misc_a   = (const float*)d_in[22];
    const float* ma_w1    = (const float*)d_in[23];
    const float* ma_w2    = (const float*)d_in[24];
    const float* misc_k   = (const float*)d_in[25];
    const float* mk_w1    = (const float*)d_in[26];
    const float* mk_w2    = (const float*)d_in[27];
    const float* faaaa    = (const float*)d_in[28];
    const float* lnw      = (const float*)d_in[29];
    const float* lnb      = (const float*)d_in[30];

    float* ws = (float*)d_ws;
    const size_t TC = (size_t)T_ * C_;
    // f32 buffers:
    //   S0: y   S2: b   S3: kk   S4: r   S5: dec   S6: k0 -> k   S7: v
    float* S0 = ws + 0 * TC;
    float* S2 = ws + 2 * TC;
    float* S3 = ws + 3 * TC;
    float* S4 = ws + 4 * TC;
    float* S5 = ws + 5 * TC;
    float* S6 = ws + 6 * TC;
    float* S7 = ws + 7 * TC;
    float* m1p = ws + 8 * TC;                    // [4][T][128] partials
    float* l2p = m1p + (size_t)4 * T_ * 128;     // [4][T][256] partials
    // f16 region
    _Float16* WTq = (_Float16*)(l2p + (size_t)4 * T_ * 256);
    _Float16* WTk = WTq + (size_t)C_ * C_;
    _Float16* WTv = WTk + (size_t)C_ * C_;
    _Float16* WTo = WTv + (size_t)C_ * C_;
    _Float16* WTm = WTo + (size_t)C_ * C_;       // [128,2048]
    _Float16* WTl = WTm + (size_t)128 * C_;      // [256,2048]
    _Float16* xxxH = WTl + (size_t)256 * C_;
    _Float16* xrgH = xxxH + TC;
    _Float16* xwaH = xrgH + TC;
    _Float16* xkH  = xwaH + TC;
    _Float16* xvH  = xkH + TC;
    _Float16* ygH  = xxxH;                       // xxxH dead after step 6
    float* out = (float*)d_out;

    // 1. transpose+convert big weights
    k_tr<<<dim3(32, 32, 4), 256, 0, stream>>>(Wq, Wk, Wv, Wo, WTq, WTk, WTv, WTo);
    // 2. pack+transpose LoRA weights (z=0: WTm, z=1: WTl)
    k_trW<<<dim3(8, 256, 2), 256, 0, stream>>>(maa_w1, gate_w1, decay_w1,
        aaa_w1, ma_w1, kkk_w1, mk_w1, WTm, WTl);
    // 3. xxxH
    k_prep<<<dim3((int)(TC / 256)), 256, 0, stream>>>(hidden, maa_x, xxxH);
    // 4. m1 partials = xxxH @ WTm^T
    k_lora<<<dim3(16, 4, 4), 256, 0, stream>>>(0, xxxH, xxxH, xxxH, xxxH,
        WTm, WTl, m1p, l2p);
    // 5. xmix -> f16 operands
    k_xmix<<<dim3(8, 64), 256, 0, stream>>>(hidden, m1p, maa_w2,
        maa_rg, maa_wa, maa_k, maa_v, xrgH, xwaH, xkH, xvH);
    // 6. l2 partials (gate | decay | aaa | ma | kkk | mk)
    k_lora<<<dim3(16, 8, 4), 256, 0, stream>>>(1, xxxH, xrgH, xwaH, xkH,
        WTm, WTl, m1p, l2p);
    // 7. r, k0, v (f16 MFMA, dbuf async staging)
    k_gemm<<<dim3(16, 8, 3), 256, 0, stream>>>(
        xrgH, WTq, S4,  xkH, WTk, S6,  xvH, WTv, S7);
    // 8. fused stage-2: dec, kk (normalized), b, k_final
    k_fuse<<<dim3(8, 64), 256, 0, stream>>>(l2p, S6, decay_w2, aaa_w2, ma_w2,
        kkk_w2, mk_w2, tdecay, aaaaa, misc_a, misc_k, S5, S3, S2);
    // 9. WKV7 scan -> y (S0)
    k_wkv<<<dim3(256), 128, 0, stream>>>(S4, S5, S6, S7, S3, S2, S0);
    // 10. groupnorm + bonus + fused gate -> f16 (reuses xxxH slot)
    k_gn<<<dim3(8, 64), 256, 0, stream>>>(S0, S4, S6, S7, l2p, gate_w2,
        faaaa, lnw, lnb, ygH);
    // 11. out = (y*g) @ Wo
    k_gemm<<<dim3(16, 8, 1), 256, 0, stream>>>(
        ygH, WTo, out,  ygH, WTo, out,  ygH, WTo, out);
}

// Round 2
// 558.134 us; speedup vs baseline: 1.0715x; 1.0262x over previous
//
#include <hip/hip_runtime.h>

// RWKV7 attention block, MI355X/gfx950.
// B=1, T=1024, C=2048, H=32, N=64. All inputs/outputs f32.
// Big GEMMs: f16 MFMA 16x16x32, double-buffered global_load_lds(16B) staging.
// LoRA stage-1: MFMA split-K, deterministic per-split partials.
// WKV scan v7: SEGMENTED two-pass scan (exact; recurrence is linear:
// state_t = state_{t-1} M_t + v_t k_t^T, M_t = diag(d_t) + a_t b_t^T).
//   pass1: per (head,seg) local end-state from 0 (z=0) AND transition
//          product P = prod(M_t) (z=1; each P row evolves like a state row,
//          init=identity, no vk source). 1024-thr blocks own all 64 rows ->
//          shared arrays staged ONCE per site (kills 8x fetch amplification),
//          16 waves/block = 4/SIMD hides LDS latency (v6 had 0.5 waves/SIMD).
//   comb:  S_in(g) = S_in(g-1) @ P(g-1) + S_end(g-1), 32 blocks, tiny.
//   pass2: replay each segment from exact S_in(g), emit Y. Critical path
//          1024 -> 128 steps/wave.

#define T_ 1024
#define C_ 2048
#define H_ 32
#define N_ 64

using half8  = __attribute__((ext_vector_type(8))) _Float16;  // 8 f16 (4 VGPRs)
using half4  = __attribute__((ext_vector_type(4))) _Float16;  // 8 B
using floatx4 = __attribute__((ext_vector_type(4))) float;    // 4 f32 acc

// DPP xor-add within 16-lane rows: quad_perm(0xB1)=xor1, quad_perm(0x4E)=xor2,
// row_half_mirror(0x141)=xor4, row_mirror(0x140)=xor8.
#define DPP_ADD(v, ctrl) \
    ((v) + __int_as_float(__builtin_amdgcn_update_dpp( \
        0, __float_as_int(v), (ctrl), 0xf, 0xf, true)))
#define REDUCE16(v) do { \
    v = DPP_ADD(v, 0xB1); v = DPP_ADD(v, 0x4E); \
    v = DPP_ADD(v, 0x141); v = DPP_ADD(v, 0x140); } while (0)

// async 16B global->LDS (direct-to-LDS DMA; HW dest = wave base + lane*16,
// all call sites construct per-lane lds ptrs matching exactly that layout)
__device__ __forceinline__ void async_cp16(const void* g, void* l) {
    __builtin_amdgcn_global_load_lds(
        (const __attribute__((address_space(1))) void*)g,
        (__attribute__((address_space(3))) void*)l, 16, 0, 0);
}

// ---------------------------------------------------------------------------
// Transpose + convert big weights: W[k][n] f32 -> WT[n][k] f16
// ---------------------------------------------------------------------------
__global__ __launch_bounds__(256) void k_tr(
    const float* __restrict__ W0, const float* __restrict__ W1,
    const float* __restrict__ W2, const float* __restrict__ W3,
    _Float16* __restrict__ D0, _Float16* __restrict__ D1,
    _Float16* __restrict__ D2, _Float16* __restrict__ D3)
{
    const int z = blockIdx.z;
    const float* S = (z == 0) ? W0 : (z == 1) ? W1 : (z == 2) ? W2 : W3;
    _Float16* D = (z == 0) ? D0 : (z == 1) ? D1 : (z == 2) ? D2 : D3;
    const int nb = blockIdx.x * 64, kb = blockIdx.y * 64;
    __shared__ __align__(16) float tile[64][65];
    const int tr = threadIdx.x >> 4, tc4 = (threadIdx.x & 15) * 4;
#pragma unroll
    for (int p = 0; p < 4; ++p) {
        int row = p * 16 + tr;
        float4 v = *(const float4*)&S[(size_t)(kb + row) * C_ + nb + tc4];
        tile[row][tc4 + 0] = v.x; tile[row][tc4 + 1] = v.y;
        tile[row][tc4 + 2] = v.z; tile[row][tc4 + 3] = v.w;
    }
    __syncthreads();
#pragma unroll
    for (int p = 0; p < 4; ++p) {
        int n = p * 16 + tr;
        half4 u;
        u[0] = (_Float16)tile[tc4 + 0][n];
        u[1] = (_Float16)tile[tc4 + 1][n];
        u[2] = (_Float16)tile[tc4 + 2][n];
        u[3] = (_Float16)tile[tc4 + 3][n];
        *(half4*)&D[(size_t)(nb + n) * C_ + kb + tc4] = u;
    }
}

// ---------------------------------------------------------------------------
// Pack+transpose LoRA weights to f16 WT[n][k].
// z=0: WT_m [128][2048] <- maa_w1[2048,128]
// z=1: WT_l [256][2048] <- gate(128) | decay(64) | aaa(16) | ma(16) | kkk(16) | mk(16)
// ---------------------------------------------------------------------------
__global__ __launch_bounds__(256) void k_trW(
    const float* __restrict__ maa_w1, const float* __restrict__ gate_w1,
    const float* __restrict__ decay_w1, const float* __restrict__ aaa_w1,
    const float* __restrict__ ma_w1, const float* __restrict__ kkk_w1,
    const float* __restrict__ mk_w1,
    _Float16* __restrict__ WTm, _Float16* __restrict__ WTl)
{
    const int z = blockIdx.z;
    const int k = blockIdx.x * 256 + threadIdx.x;   // 0..2047
    const int n = blockIdx.y;
    if (z == 0 && n >= 128) return;
    const float* src; int stride, col;
    _Float16* dst;
    if (z == 0) { src = maa_w1; stride = 128; col = n; dst = WTm; }
    else {
        dst = WTl;
        if (n < 128)      { src = gate_w1;  stride = 128; col = n; }
        else if (n < 192) { src = decay_w1; stride = 64;  col = n - 128; }
        else if (n < 208) { src = aaa_w1;   stride = 16;  col = n - 192; }
        else if (n < 224) { src = ma_w1;    stride = 16;  col = n - 208; }
        else if (n < 240) { src = kkk_w1;   stride = 16;  col = n - 224; }
        else              { src = mk_w1;    stride = 16;  col = n - 240; }
    }
    dst[(size_t)n * C_ + k] = (_Float16)src[(size_t)k * stride + col];
}

// ---------------------------------------------------------------------------
// xxxH = f16( x + (x_prev - x) * maa_x )
// ---------------------------------------------------------------------------
__global__ __launch_bounds__(256) void k_prep(
    const float* __restrict__ X, const float* __restrict__ maa_x,
    _Float16* __restrict__ xxxH)
{
    const size_t idx = (size_t)blockIdx.x * 256 + threadIdx.x;
    const int c = (int)(idx & (C_ - 1));
    float cur = X[idx];
    float prev = (idx >= C_) ? X[idx - C_] : 0.0f;
    xxxH[idx] = (_Float16)(cur + (prev - cur) * maa_x[c]);
}

// ---------------------------------------------------------------------------
// LoRA MFMA GEMM, split-K -> per-split partials (deterministic; no atomics).
// BM=64, BN=32, BK=32, ksplit=4.
// which=0: m1p[ks][1024][128] = xxxH @ WTm^T (4 n-tiles)
// which=1: l2p[ks][1024][256], A per n-tile: 0-3 xrg | 4-6 xwa | 7 xk
// ---------------------------------------------------------------------------
__global__ __launch_bounds__(256) void k_lora(
    int which,
    const _Float16* __restrict__ Axxx, const _Float16* __restrict__ Axrg,
    const _Float16* __restrict__ Axwa, const _Float16* __restrict__ Axk,
    const _Float16* __restrict__ WTm, const _Float16* __restrict__ WTl,
    float* __restrict__ m1p, float* __restrict__ l2p)
{
    const int mt = blockIdx.x;      // 16 tiles of 64 rows
    const int nt = blockIdx.y;      // tiles of 32 cols
    const int ks = blockIdx.z;      // 4 K-chunks of 512
    const _Float16* A; const _Float16* BT; float* O; int ostride;
    if (which == 0) { A = Axxx; BT = WTm; O = m1p; ostride = 128; }
    else {
        BT = WTl; O = l2p; ostride = 256;
        A = (nt < 4) ? Axrg : (nt < 7) ? Axwa : Axk;
    }
    O += (size_t)ks * T_ * ostride;
    const int m0 = mt * 64, n0 = nt * 32, k0 = ks * 512;
    const int tid = threadIdx.x;
    __shared__ __align__(16) _Float16 As[64 * 40];
    __shared__ __align__(16) _Float16 Bs[32 * 40];
    const int lane = tid & 63, wv = tid >> 6;
    const int r16 = lane & 15, q = lane >> 4;

    floatx4 acc[2];
    { floatx4 zv = {0.f, 0.f, 0.f, 0.f}; acc[0] = zv; acc[1] = zv; }

    const int arow = tid >> 2, ac8 = (tid & 3) * 8;
    const _Float16* ag = A + (size_t)(m0 + arow) * C_ + k0 + ac8;
    const _Float16* bg = BT + (size_t)(n0 + (tid >> 2)) * C_ + k0 + ac8;

    for (int kc = 0; kc < 512; kc += 32) {
        half8 av = *(const half8*)(ag + kc);
        half8 bv;
        if (tid < 128) bv = *(const half8*)(bg + kc);
        *(half8*)&As[arow * 40 + ac8] = av;
        if (tid < 128) *(half8*)&Bs[(tid >> 2) * 40 + ac8] = bv;
        __syncthreads();
        half8 af = *(const half8*)&As[(wv * 16 + r16) * 40 + q * 8];
        half8 b0 = *(const half8*)&Bs[(r16) * 40 + q * 8];
        half8 b1 = *(const half8*)&Bs[(16 + r16) * 40 + q * 8];
        acc[0] = __builtin_amdgcn_mfma_f32_16x16x32_f16(af, b0, acc[0], 0, 0, 0);
        acc[1] = __builtin_amdgcn_mfma_f32_16x16x32_f16(af, b1, acc[1], 0, 0, 0);
        __syncthreads();
    }
#pragma unroll
    for (int j = 0; j < 2; ++j)
#pragma unroll
        for (int e = 0; e < 4; ++e) {
            int row = m0 + wv * 16 + q * 4 + e;
            int col = n0 + j * 16 + r16;
            O[(size_t)row * ostride + col] = acc[j][e];
        }
}

// ---------------------------------------------------------------------------
// xmix: m1 = sum_ks(m1p), tanh; mix = einsum(m1[T,4,32], maa_w2[4,32,C]);
// emit f16 GEMM operands xrgH/xwaH/xkH/xvH.
// ---------------------------------------------------------------------------
__global__ __launch_bounds__(256) void k_xmix(
    const float* __restrict__ X, const float* __restrict__ m1p,
    const float* __restrict__ w2,
    const float* __restrict__ mrg, const float* __restrict__ mwa,
    const float* __restrict__ mk, const float* __restrict__ mv,
    _Float16* __restrict__ xrgH, _Float16* __restrict__ xwaH,
    _Float16* __restrict__ xkH, _Float16* __restrict__ xvH)
{
    const int tid = threadIdx.x;
    const int c = blockIdx.x * 256 + tid;
    const int t0 = blockIdx.y * 16;
    const size_t P = (size_t)T_ * 128;
    __shared__ __align__(16) float m1s[16][128];
#pragma unroll
    for (int p = 0; p < 2; ++p) {
        int id = tid + p * 256;
        int r = id >> 5, c4 = (id & 31) * 4;
        size_t off = (size_t)(t0 + r) * 128 + c4;
        float4 v0 = *(const float4*)&m1p[off];
        float4 v1 = *(const float4*)&m1p[P + off];
        float4 v2 = *(const float4*)&m1p[2 * P + off];
        float4 v3 = *(const float4*)&m1p[3 * P + off];
        float4 v;
        v.x = tanhf(((v0.x + v1.x) + v2.x) + v3.x);
        v.y = tanhf(((v0.y + v1.y) + v2.y) + v3.y);
        v.z = tanhf(((v0.z + v1.z) + v2.z) + v3.z);
        v.w = tanhf(((v0.w + v1.w) + v2.w) + v3.w);
        *(float4*)&m1s[r][c4] = v;
    }
    __syncthreads();
    float a0[16], a1[16], a2[16], a3[16];
#pragma unroll
    for (int t = 0; t < 16; ++t) { a0[t] = 0.f; a1[t] = 0.f; a2[t] = 0.f; a3[t] = 0.f; }
    for (int d = 0; d < 32; ++d) {
        float w0 = w2[(size_t)(0 * 32 + d) * C_ + c];
        float w1 = w2[(size_t)(1 * 32 + d) * C_ + c];
        float w2v = w2[(size_t)(2 * 32 + d) * C_ + c];
        float w3 = w2[(size_t)(3 * 32 + d) * C_ + c];
#pragma unroll
        for (int t = 0; t < 16; ++t) {
            a0[t] = fmaf(m1s[t][d],      w0,  a0[t]);
            a1[t] = fmaf(m1s[t][32 + d], w1,  a1[t]);
            a2[t] = fmaf(m1s[t][64 + d], w2v, a2[t]);
            a3[t] = fmaf(m1s[t][96 + d], w3,  a3[t]);
        }
    }
    float vrg = mrg[c], vwa = mwa[c], vmk = mk[c], vmv = mv[c];
    float prev = (t0 > 0) ? X[(size_t)(t0 - 1) * C_ + c] : 0.0f;
    for (int t = 0; t < 16; ++t) {
        size_t idx = (size_t)(t0 + t) * C_ + c;
        float cur = X[idx];
        float dx = prev - cur;
        xrgH[idx] = (_Float16)(cur + dx * (vrg + a0[t]));
        xwaH[idx] = (_Float16)(cur + dx * (vwa + a1[t]));
        xkH[idx]  = (_Float16)(cur + dx * (vmk + a2[t]));
        xvH[idx]  = (_Float16)(cur + dx * (vmv + a3[t]));
        prev = cur;
    }
}

// ---------------------------------------------------------------------------
// f16 MFMA GEMM: C[1024,2048] = A(f16) @ W via WT[n][k] f16.
// BM=BN=128, BK=32, 256 thr (4 waves 2x2), 4x4 16x16x32 tiles/wave.
// Double-buffered global_load_lds staging.
// ---------------------------------------------------------------------------
__global__ __launch_bounds__(256) void k_gemm(
    const _Float16* __restrict__ A0, const _Float16* __restrict__ B0, float* __restrict__ C0,
    const _Float16* __restrict__ A1, const _Float16* __restrict__ B1, float* __restrict__ C1,
    const _Float16* __restrict__ A2, const _Float16* __restrict__ B2, float* __restrict__ C2)
{
    const int z = blockIdx.z;
    const _Float16* A = (z == 0) ? A0 : (z == 1) ? A1 : A2;
    const _Float16* Bt = (z == 0) ? B0 : (z == 1) ? B1 : B2;
    float* C = (z == 0) ? C0 : (z == 1) ? C1 : C2;
    const int mtile = blockIdx.y * 128;
    const int ntile = blockIdx.x * 128;
    const int tid = threadIdx.x;
    __shared__ __align__(16) _Float16 As[2][128 * 32];  // unpadded (async layout)
    __shared__ __align__(16) _Float16 Bs[2][128 * 32];
    const int lane = tid & 63;
    const int wvid = tid >> 6;
    const int wm = wvid >> 1, wn = wvid & 1;
    const int r16 = lane & 15, q = lane >> 4;

    floatx4 acc[4][4];
#pragma unroll
    for (int i = 0; i < 4; ++i)
#pragma unroll
        for (int j = 0; j < 4; ++j) { floatx4 zv = {0.f, 0.f, 0.f, 0.f}; acc[i][j] = zv; }

    const int srow = tid >> 2, sq = tid & 3;
    const _Float16* agA = A + (size_t)(mtile + srow) * C_ + sq * 8;
    const _Float16* agB = Bt + (size_t)(ntile + srow) * C_ + sq * 8;
    const int ldso = srow * 32 + sq * 8;
    const size_t rowoff = (size_t)64 * C_;

    async_cp16(agA, &As[0][ldso]);
    async_cp16(agA + rowoff, &As[0][ldso + 64 * 32]);
    async_cp16(agB, &Bs[0][ldso]);
    async_cp16(agB + rowoff, &Bs[0][ldso + 64 * 32]);

    for (int kc = 0; kc < C_; kc += 32) {
        const int p = (kc >> 5) & 1;
        __syncthreads();                      // buf p ready (drains copies)
        if (kc + 32 < C_) {                   // prefetch k+1 into buf p^1
            async_cp16(agA + kc + 32, &As[p ^ 1][ldso]);
            async_cp16(agA + kc + 32 + rowoff, &As[p ^ 1][ldso + 64 * 32]);
            async_cp16(agB + kc + 32, &Bs[p ^ 1][ldso]);
            async_cp16(agB + kc + 32 + rowoff, &Bs[p ^ 1][ldso + 64 * 32]);
        }
        half8 af[4], bf[4];
#pragma unroll
        for (int i = 0; i < 4; ++i)
            af[i] = *(const half8*)&As[p][(wm * 64 + i * 16 + r16) * 32 + q * 8];
#pragma unroll
        for (int j = 0; j < 4; ++j)
            bf[j] = *(const half8*)&Bs[p][(wn * 64 + j * 16 + r16) * 32 + q * 8];
#pragma unroll
        for (int i = 0; i < 4; ++i)
#pragma unroll
            for (int j = 0; j < 4; ++j)
                acc[i][j] = __builtin_amdgcn_mfma_f32_16x16x32_f16(af[i], bf[j], acc[i][j], 0, 0, 0);
    }
    // C/D layout: col = lane&15, row = (lane>>4)*4 + reg
#pragma unroll
    for (int i = 0; i < 4; ++i)
#pragma unroll
        for (int j = 0; j < 4; ++j)
#pragma unroll
            for (int e = 0; e < 4; ++e) {
                int row = mtile + wm * 64 + i * 16 + q * 4 + e;
                int col = ntile + wn * 64 + j * 16 + r16;
                C[(size_t)row * C_ + col] = acc[i][j][e];
            }
}

// ---------------------------------------------------------------------------
// Fused stage-2: dec=exp(w), kk (normalized), b = kk*a, k_final.
// l2p partials [4][T][256]: cols 128-191 decay(tanh) | 192-207 aaa |
// 208-223 ma | 224-239 kkk(tanh) | 240-255 mk. Fixed-order reduce.
// ---------------------------------------------------------------------------
__global__ __launch_bounds__(256) void k_fuse(
    const float* __restrict__ l2p,
    float* __restrict__ K0,
    const float* __restrict__ decay_w2, const float* __restrict__ aaa_w2,
    const float* __restrict__ ma_w2, const float* __restrict__ kkk_w2,
    const float* __restrict__ mk_w2,
    const float* __restrict__ tdecay, const float* __restrict__ aaaaa,
    const float* __restrict__ misc_a, const float* __restrict__ misc_k,
    float* __restrict__ Dout, float* __restrict__ KKout, float* __restrict__ Bout)
{
    const int tid = threadIdx.x;
    const int c = blockIdx.x * 256 + tid;
    const int t0 = blockIdx.y * 16;
    const size_t P = (size_t)T_ * 256;
    __shared__ __align__(16) float wsS[16][96];   // decay64 | aaa16 | ma16
    __shared__ __align__(16) float ksS[16][32];   // kkk16 | mk16
    for (int id = tid; id < 16 * 24; id += 256) {
        int r = id / 24, c4 = (id % 24) * 4;
        size_t off = (size_t)(t0 + r) * 256 + 128 + c4;
        float4 v0 = *(const float4*)&l2p[off];
        float4 v1 = *(const float4*)&l2p[P + off];
        float4 v2 = *(const float4*)&l2p[2 * P + off];
        float4 v3 = *(const float4*)&l2p[3 * P + off];
        float4 v;
        v.x = ((v0.x + v1.x) + v2.x) + v3.x;
        v.y = ((v0.y + v1.y) + v2.y) + v3.y;
        v.z = ((v0.z + v1.z) + v2.z) + v3.z;
        v.w = ((v0.w + v1.w) + v2.w) + v3.w;
        if (c4 < 64) { v.x = tanhf(v.x); v.y = tanhf(v.y); v.z = tanhf(v.z); v.w = tanhf(v.w); }
        *(float4*)&wsS[r][c4] = v;
    }
    for (int id = tid; id < 16 * 8; id += 256) {
        int r = id / 8, c4 = (id % 8) * 4;
        size_t off = (size_t)(t0 + r) * 256 + 224 + c4;
        float4 v0 = *(const float4*)&l2p[off];
        float4 v1 = *(const float4*)&l2p[P + off];
        float4 v2 = *(const float4*)&l2p[2 * P + off];
        float4 v3 = *(const float4*)&l2p[3 * P + off];
        float4 v;
        v.x = ((v0.x + v1.x) + v2.x) + v3.x;
        v.y = ((v0.y + v1.y) + v2.y) + v3.y;
        v.z = ((v0.z + v1.z) + v2.z) + v3.z;
        v.w = ((v0.w + v1.w) + v2.w) + v3.w;
        if (c4 < 16) { v.x = tanhf(v.x); v.y = tanhf(v.y); v.z = tanhf(v.z); v.w = tanhf(v.w); }
        *(float4*)&ksS[r][c4] = v;
    }
    __syncthreads();
    float accW[16], accA[16], accMA[16], accKK[16], accMK[16];
#pragma unroll
    for (int r = 0; r < 16; ++r) { accW[r] = 0.f; accA[r] = 0.f; accMA[r] = 0.f; accKK[r] = 0.f; accMK[r] = 0.f; }
    for (int j = 0; j < 64; ++j) {
        float w = decay_w2[(size_t)j * C_ + c];
#pragma unroll
        for (int r = 0; r < 16; ++r) accW[r] = fmaf(wsS[r][j], w, accW[r]);
    }
    for (int j = 0; j < 16; ++j) {
        float wa = aaa_w2[(size_t)j * C_ + c];
        float wm = ma_w2[(size_t)j * C_ + c];
        float wk = kkk_w2[(size_t)j * C_ + c];
        float wq = mk_w2[(size_t)j * C_ + c];
#pragma unroll
        for (int r = 0; r < 16; ++r) {
            accA[r]  = fmaf(wsS[r][64 + j], wa, accA[r]);
            accMA[r] = fmaf(wsS[r][80 + j], wm, accMA[r]);
            accKK[r] = fmaf(ksS[r][j],      wk, accKK[r]);
            accMK[r] = fmaf(ksS[r][16 + j], wq, accMK[r]);
        }
    }
    float td = tdecay[c], aa = aaaaa[c], mia = misc_a[c], mik = misc_k[c];
    for (int r = 0; r < 16; ++r) {
        size_t idx = (size_t)(t0 + r) * C_ + c;
        float wraw = td + accW[r];
        float w = -logf(1.0f + __expf(-wraw)) - 0.5f;   // -softplus(-x) - 0.5
        float a  = 1.0f / (1.0f + __expf(-(aa  + accA[r])));
        float mav = 1.0f / (1.0f + __expf(-(mia + accMA[r])));
        float mkv = 1.0f / (1.0f + __expf(-(mik + accMK[r])));
        float k0 = K0[idx];
        float kkun = k0 + accKK[r];
        float ss = kkun * kkun;
        REDUCE16(ss);
        ss += __shfl_xor(ss, 16, 64);
        ss += __shfl_xor(ss, 32, 64);
        float kn = kkun * (1.0f / fmaxf(sqrtf(ss), 1e-12f));
        Dout[idx]  = __expf(w);                 // dec, precomputed for the scan
        KKout[idx] = kn;
        Bout[idx]  = kn * a;
        K0[idx]    = k0 * (mav + a * (1.0f - mav)) * __expf(fminf(w * mkv, 0.0f));
    }
}

// ---------------------------------------------------------------------------
// WKV7 segmented scan, pass 1. Grid (7 segs, 32 heads, 2 types), 1024 thr
// (16 waves x 4 rowslots = 64 rows; 16 lanes x float4 = 64 cols per row).
// type z=0: S_local — init 0, full update with v k^T source -> Send.
// type z=1: P       — init identity, no source (row p <- p*d + (p.a)b) -> Pend.
// Shared per-t arrays staged ONCE per block (64 rows share them).
// ---------------------------------------------------------------------------
__global__ __launch_bounds__(1024) void k_wkv_p1(
    const float* __restrict__ DEC, const float* __restrict__ K,
    const float* __restrict__ V, const float* __restrict__ KK,
    const float* __restrict__ Bb,
    float* __restrict__ Send, float* __restrict__ Pend)
{
    const int tid = threadIdx.x;
    const int g = blockIdx.x;                  // segment 0..6
    const int h = blockIdx.y;                  // head
    const bool isP = blockIdx.z != 0;
    const int c0 = h * 64;
    const int wv = tid >> 6, lane = tid & 63;
    const int row = wv * 4 + (lane >> 4);      // 0..63
    const int jg = lane & 15, j4 = jg * 4;

    __shared__ __align__(16) float dS[2][16][64], aS[2][16][64], bS[2][16][64],
                                   kS[2][16][64], vS[2][16][64];

    // staging: pos in [0,256) covers one 4KB array-chunk (16 steps x 64 cols);
    // grp selects which array this thread stages. Per-wave lds dest =
    // wave-uniform base + lane*16 (DMA constraint holds: pos = wavebase+lane).
    const int pos = tid & 255, grp = tid >> 8;
    const int pst = pos >> 4, pq4 = (pos & 15) * 4;

#define P1_STAGE(buf, tcb) do {                                               \
    size_t gg = (size_t)((tcb) + pst) * C_ + c0 + pq4;                        \
    if (grp == 0)      async_cp16(&DEC[gg], &dS[buf][pst][pq4]);              \
    else if (grp == 2) async_cp16(&KK[gg],  &aS[buf][pst][pq4]);              \
    else if (grp == 3) async_cp16(&Bb[gg],  &bS[buf][pst][pq4]);              \
    if (!isP) {                                                               \
        if (grp == 1)      async_cp16(&K[gg], &kS[buf][pst][pq4]);            \
        else if (grp == 0) async_cp16(&V[gg], &vS[buf][pst][pq4]);            \
    }                                                                         \
} while (0)

    float4 s;
    if (isP) {
        s.x = (j4 + 0 == row) ? 1.f : 0.f;
        s.y = (j4 + 1 == row) ? 1.f : 0.f;
        s.z = (j4 + 2 == row) ? 1.f : 0.f;
        s.w = (j4 + 3 == row) ? 1.f : 0.f;
    } else {
        s = make_float4(0.f, 0.f, 0.f, 0.f);
    }

    const int t0 = g * 128;
    P1_STAGE(0, t0);

    if (isP) {
        for (int tc = 0; tc < 128; tc += 16) {
            const int p = (tc >> 4) & 1;
            __syncthreads();                               // buf p ready
            if (tc + 16 < 128) P1_STAGE(p ^ 1, t0 + tc + 16);
#pragma unroll
            for (int tt = 0; tt < 16; ++tt) {
                float4 cd = *(float4*)&dS[p][tt][j4];
                float4 ca = *(float4*)&aS[p][tt][j4];
                float4 cb = *(float4*)&bS[p][tt][j4];
                float d01 = fmaf(s.y, ca.y, s.x * ca.x);
                float d23 = fmaf(s.w, ca.w, s.z * ca.z);
                float sa = -(d01 + d23);
                REDUCE16(sa);
                s.x = fmaf(s.x, cd.x, sa * cb.x);
                s.y = fmaf(s.y, cd.y, sa * cb.y);
                s.z = fmaf(s.z, cd.z, sa * cb.z);
                s.w = fmaf(s.w, cd.w, sa * cb.w);
            }
        }
        *(float4*)&Pend[(size_t)((h * 7 + g) * 64 + row) * 64 + j4] = s;
    } else {
        for (int tc = 0; tc < 128; tc += 16) {
            const int p = (tc >> 4) & 1;
            __syncthreads();                               // buf p ready
            if (tc + 16 < 128) P1_STAGE(p ^ 1, t0 + tc + 16);
#pragma unroll
            for (int tt = 0; tt < 16; ++tt) {
                float4 cd = *(float4*)&dS[p][tt][j4];
                float4 ca = *(float4*)&aS[p][tt][j4];
                float4 cb = *(float4*)&bS[p][tt][j4];
                float4 ck = *(float4*)&kS[p][tt][j4];
                float  cv = vS[p][tt][row];
                float d01 = fmaf(s.y, ca.y, s.x * ca.x);
                float d23 = fmaf(s.w, ca.w, s.z * ca.z);
                float sa = -(d01 + d23);
                REDUCE16(sa);
                s.x = fmaf(s.x, cd.x, fmaf(sa, cb.x, cv * ck.x));
                s.y = fmaf(s.y, cd.y, fmaf(sa, cb.y, cv * ck.y));
                s.z = fmaf(s.z, cd.z, fmaf(sa, cb.z, cv * ck.z));
                s.w = fmaf(s.w, cd.w, fmaf(sa, cb.w, cv * ck.w));
            }
        }
        *(float4*)&Send[(size_t)((h * 7 + g) * 64 + row) * 64 + j4] = s;
    }
#undef P1_STAGE
}

// ---------------------------------------------------------------------------
// WKV7 segmented scan, combine. 32 blocks (1/head) x 256 thr.
// Sin(h,0) = 0; Sin(h,g) = Sin(h,g-1) @ P(h,g-1) + Send(h,g-1), g=1..7.
// Thread t: row i = t>>2, cols jq..jq+15 where jq = (t&3)*16.
// ---------------------------------------------------------------------------
__global__ __launch_bounds__(256) void k_wkv_comb(
    const float* __restrict__ Send, const float* __restrict__ Pend,
    float* __restrict__ Sin)
{
    const int h = blockIdx.x;
    const int tid = threadIdx.x;
    const int i = tid >> 2;
    const int jq = (tid & 3) * 16;
    __shared__ float Sc[64][65];               // padded: Sc[i][k] conflict-free
    __shared__ __align__(16) float Pl[64][64];

    float4 z4 = make_float4(0.f, 0.f, 0.f, 0.f);
#pragma unroll
    for (int c = 0; c < 16; c += 4)
        *(float4*)&Sin[(size_t)(h * 8) * 4096 + (size_t)i * 64 + jq + c] = z4;
#pragma unroll
    for (int c = 0; c < 16; ++c) Sc[i][jq + c] = 0.f;
    __syncthreads();

    for (int g = 1; g < 8; ++g) {
        const float* Pg = &Pend[(size_t)(h * 7 + g - 1) * 4096];
        for (int idx = tid * 4; idx < 4096; idx += 1024) {
            float4 v = *(const float4*)&Pg[idx];
            *(float4*)&Pl[idx >> 6][idx & 63] = v;
        }
        __syncthreads();
        float acc[16];
        const float* Sg = &Send[(size_t)(h * 7 + g - 1) * 4096 + (size_t)i * 64 + jq];
#pragma unroll
        for (int c = 0; c < 16; c += 4) {
            float4 v = *(const float4*)&Sg[c];
            acc[c] = v.x; acc[c + 1] = v.y; acc[c + 2] = v.z; acc[c + 3] = v.w;
        }
        for (int k = 0; k < 64; ++k) {
            float sik = Sc[i][k];
#pragma unroll
            for (int c = 0; c < 16; ++c) acc[c] = fmaf(sik, Pl[k][jq + c], acc[c]);
        }
        __syncthreads();                       // all reads of Sc/Pl done
        float* So = &Sin[(size_t)(h * 8 + g) * 4096 + (size_t)i * 64 + jq];
#pragma unroll
        for (int c = 0; c < 16; ++c) Sc[i][jq + c] = acc[c];
#pragma unroll
        for (int c = 0; c < 16; c += 4) {
            float4 v = make_float4(acc[c], acc[c + 1], acc[c + 2], acc[c + 3]);
            *(float4*)&So[c] = v;
        }
        __syncthreads();                       // Sc updated for next g
    }
}

// ---------------------------------------------------------------------------
// WKV7 segmented scan, pass 2. Grid (8 segs, 32 heads), 1024 thr (64 rows).
// Replay segment from exact Sin(h,g), emit Y. Output reductions deferred in
// half-chunks of 8 (po[8] caps VGPR under the 1024-thr/128-reg limit).
// ---------------------------------------------------------------------------
__global__ __launch_bounds__(1024) void k_wkv_p2(
    const float* __restrict__ R, const float* __restrict__ DEC,
    const float* __restrict__ K, const float* __restrict__ V,
    const float* __restrict__ KK, const float* __restrict__ Bb,
    const float* __restrict__ Sin, float* __restrict__ Y)
{
    const int tid = threadIdx.x;
    const int g = blockIdx.x;                  // segment 0..7
    const int h = blockIdx.y;
    const int c0 = h * 64;
    const int wv = tid >> 6, lane = tid & 63;
    const int row = wv * 4 + (lane >> 4);      // 0..63
    const int jg = lane & 15, j4 = jg * 4;

    __shared__ __align__(16) float rS[2][16][64], dS[2][16][64], kS[2][16][64],
                                   aS[2][16][64], bS[2][16][64], vS[2][16][64];

    const int pos = tid & 255, grp = tid >> 8;
    const int pst = pos >> 4, pq4 = (pos & 15) * 4;

#define P2_STAGE(buf, tcb) do {                                               \
    size_t gg = (size_t)((tcb) + pst) * C_ + c0 + pq4;                        \
    if (grp == 0)      { async_cp16(&R[gg], &rS[buf][pst][pq4]);              \
                         async_cp16(&K[gg], &kS[buf][pst][pq4]); }            \
    else if (grp == 1) { async_cp16(&DEC[gg], &dS[buf][pst][pq4]);            \
                         async_cp16(&V[gg],   &vS[buf][pst][pq4]); }          \
    else if (grp == 2) async_cp16(&KK[gg], &aS[buf][pst][pq4]);               \
    else               async_cp16(&Bb[gg], &bS[buf][pst][pq4]);               \
} while (0)

    float4 s = *(const float4*)&Sin[(size_t)((h * 8 + g) * 64 + row) * 64 + j4];

    const int t0 = g * 128;
    P2_STAGE(0, t0);

    for (int tc = 0; tc < 128; tc += 16) {
        const int p = (tc >> 4) & 1;
        __syncthreads();                               // buf p ready
        if (tc + 16 < 128) P2_STAGE(p ^ 1, t0 + tc + 16);
#pragma unroll
        for (int hh = 0; hh < 2; ++hh) {
            float po[8];
#pragma unroll
            for (int q = 0; q < 8; ++q) {
                const int tt = hh * 8 + q;
                float4 cr = *(float4*)&rS[p][tt][j4];
                float4 cd = *(float4*)&dS[p][tt][j4];
                float4 ck = *(float4*)&kS[p][tt][j4];
                float4 ca = *(float4*)&aS[p][tt][j4];
                float4 cb = *(float4*)&bS[p][tt][j4];
                float  cv = vS[p][tt][row];
                float d01 = fmaf(s.y, ca.y, s.x * ca.x);
                float d23 = fmaf(s.w, ca.w, s.z * ca.z);
                float sa = -(d01 + d23);
                REDUCE16(sa);
                s.x = fmaf(s.x, cd.x, fmaf(sa, cb.x, cv * ck.x));
                s.y = fmaf(s.y, cd.y, fmaf(sa, cb.y, cv * ck.y));
                s.z = fmaf(s.z, cd.z, fmaf(sa, cb.z, cv * ck.z));
                s.w = fmaf(s.w, cd.w, fmaf(sa, cb.w, cv * ck.w));
                po[q] = fmaf(s.w, cr.w, fmaf(s.z, cr.z, fmaf(s.y, cr.y, s.x * cr.x)));
            }
#pragma unroll
            for (int q = 0; q < 8; ++q) REDUCE16(po[q]);
            if (jg == 0) {
#pragma unroll
                for (int q = 0; q < 8; ++q)
                    Y[(size_t)(t0 + tc + hh * 8 + q) * C_ + c0 + row] = po[q];
            }
        }
    }
#undef P2_STAGE
}

// ---------------------------------------------------------------------------
// GroupNorm + bonus + fused gate, t-tiled (16 t/block so the 128 gw2 loads
// amortize): YG = f16((gn(y) + bonus) * (tanh(l2 sum) @ gate_w2)).
// ---------------------------------------------------------------------------
__global__ __launch_bounds__(256) void k_gn(
    const float* __restrict__ Y, const float* __restrict__ R, const float* __restrict__ K,
    const float* __restrict__ V, const float* __restrict__ l2p,
    const float* __restrict__ gw2,
    const float* __restrict__ faaaa, const float* __restrict__ lnw,
    const float* __restrict__ lnb, _Float16* __restrict__ YG)
{
    const int tid = threadIdx.x;
    const int c = blockIdx.x * 256 + tid;
    const int t0 = blockIdx.y * 16;
    const size_t P = (size_t)T_ * 256;
    __shared__ __align__(16) float gs[16][128];
    for (int id = tid; id < 16 * 128; id += 256) {
        int r = id >> 7, cc = id & 127;
        size_t off = (size_t)(t0 + r) * 256 + cc;
        float v = ((l2p[off] + l2p[P + off]) + l2p[2 * P + off]) + l2p[3 * P + off];
        gs[r][cc] = tanhf(v);
    }
    __syncthreads();
    float gacc[16];
#pragma unroll
    for (int r = 0; r < 16; ++r) gacc[r] = 0.f;
    for (int j = 0; j < 128; ++j) {
        float w = gw2[(size_t)j * C_ + c];
#pragma unroll
        for (int r = 0; r < 16; ++r) gacc[r] = fmaf(gs[r][j], w, gacc[r]);
    }
    float fa = faaaa[c], lw = lnw[c], lb = lnb[c];
    for (int r = 0; r < 16; ++r) {
        const size_t idx = (size_t)(t0 + r) * C_ + c;
        float y = Y[idx];
        float s1 = y, s2 = y * y;
#pragma unroll
        for (int off = 1; off < 64; off <<= 1) {
            s1 += __shfl_xor(s1, off, 64);
            s2 += __shfl_xor(s2, off, 64);
        }
        float mu = s1 * (1.0f / 64.0f);
        float var = s2 * (1.0f / 64.0f) - mu * mu;
        float gn = (y - mu) * rsqrtf(var + 0.00064f) * lw + lb;
        float p = R[idx] * K[idx] * fa;
#pragma unroll
        for (int off = 1; off < 64; off <<= 1) p += __shfl_xor(p, off, 64);
        float y2 = gn + p * V[idx];
        YG[idx] = (_Float16)(y2 * gacc[r]);
    }
}

// ---------------------------------------------------------------------------
extern "C" void kernel_launch(void* const* d_in, const int* in_sizes, int n_in,
                              void* d_out, int out_size, void* d_ws, size_t ws_size,
                              hipStream_t stream)
{
    (void)in_sizes; (void)n_in; (void)out_size; (void)ws_size;
    const float* hidden   = (const float*)d_in[0];
    const float* Wq       = (const float*)d_in[1];
    const float* Wk       = (const float*)d_in[2];
    const float* Wv       = (const float*)d_in[3];
    const float* Wo       = (const float*)d_in[4];
    const float* maa_x    = (const float*)d_in[5];
    const float* maa_rg   = (const float*)d_in[6];
    const float* maa_wa   = (const float*)d_in[7];
    const float* maa_k    = (const float*)d_in[8];
    const float* maa_v    = (const float*)d_in[9];
    const float* maa_w1   = (const float*)d_in[10];
    const float* maa_w2   = (const float*)d_in[11];
    const float* tdecay   = (const float*)d_in[12];
    const float* decay_w1 = (const float*)d_in[13];
    const float* decay_w2 = (const float*)d_in[14];
    const float* aaaaa    = (const float*)d_in[15];
    const float* aaa_w1   = (const float*)d_in[16];
    const float* aaa_w2   = (const float*)d_in[17];
    const float* kkk_w1   = (const float*)d_in[18];
    const float* kkk_w2   = (const float*)d_in[19];
    const float* gate_w1  = (const float*)d_in[20];
    const float* gate_w2  = (const float*)d_in[21];
    const float* misc_a   = (const float*)d_in[22];
    const float* ma_w1    = (const float*)d_in[23];
    const float* ma_w2    = (const float*)d_in[24];
    const float* misc_k   = (const float*)d_in[25];
    const float* mk_w1    = (const float*)d_in[26];
    const float* mk_w2    = (const float*)d_in[27];
    const float* faaaa    = (const float*)d_in[28];
    const float* lnw      = (const float*)d_in[29];
    const float* lnb      = (const float*)d_in[30];

    float* ws = (float*)d_ws;
    const size_t TC = (size_t)T_ * C_;
    // f32 buffers:
    //   S0: y   S2: b   S3: kk   S4: r   S5: dec   S6: k0 -> k   S7: v
    //   S1 slot (8MB) repurposed: Send [32][7][64][64] + Pend [32][7][64][64]
    float* S0 = ws + 0 * TC;
    float* Send = ws + 1 * TC;                   // 917504 floats
    float* Pend = Send + (size_t)32 * 7 * 64 * 64;
    float* S2 = ws + 2 * TC;
    float* S3 = ws + 3 * TC;
    float* S4 = ws + 4 * TC;
    float* S5 = ws + 5 * TC;
    float* S6 = ws + 6 * TC;
    float* S7 = ws + 7 * TC;
    float* m1p = ws + 8 * TC;                    // [4][T][128] partials
    float* l2p = m1p + (size_t)4 * T_ * 128;     // [4][T][256] partials
    // f16 region
    _Float16* WTq = (_Float16*)(l2p + (size_t)4 * T_ * 256);
    _Float16* WTk = WTq + (size_t)C_ * C_;
    _Float16* WTv = WTk + (size_t)C_ * C_;
    _Float16* WTo = WTv + (size_t)C_ * C_;
    _Float16* WTm = WTo + (size_t)C_ * C_;       // [128,2048]
    _Float16* WTl = WTm + (size_t)128 * C_;      // [256,2048]
    _Float16* xxxH = WTl + (size_t)256 * C_;
    _Float16* xrgH = xxxH + TC;
    _Float16* xwaH = xrgH + TC;
    _Float16* xkH  = xwaH + TC;
    _Float16* xvH  = xkH + TC;
    _Float16* ygH  = xxxH;                       // xxxH dead after step 6
    // xrgH dead after step 7 -> reuse its 4MB as Sin [32][8][64][64] f32
    float* Sin = (float*)xrgH;
    float* out = (float*)d_out;

    // 1. transpose+convert big weights
    k_tr<<<dim3(32, 32, 4), 256, 0, stream>>>(Wq, Wk, Wv, Wo, WTq, WTk, WTv, WTo);
    // 2. pack+transpose LoRA weights (z=0: WTm, z=1: WTl)
    k_trW<<<dim3(8, 256, 2), 256, 0, stream>>>(maa_w1, gate_w1, decay_w1,
        aaa_w1, ma_w1, kkk_w1, mk_w1, WTm, WTl);
    // 3. xxxH
    k_prep<<<dim3((int)(TC / 256)), 256, 0, stream>>>(hidden, maa_x, xxxH);
    // 4. m1 partials = xxxH @ WTm^T
    k_lora<<<dim3(16, 4, 4), 256, 0, stream>>>(0, xxxH, xxxH, xxxH, xxxH,
        WTm, WTl, m1p, l2p);
    // 5. xmix -> f16 operands
    k_xmix<<<dim3(8, 64), 256, 0, stream>>>(hidden, m1p, maa_w2,
        maa_rg, maa_wa, maa_k, maa_v, xrgH, xwaH, xkH, xvH);
    // 6. l2 partials (gate | decay | aaa | ma | kkk | mk)
    k_lora<<<dim3(16, 8, 4), 256, 0, stream>>>(1, xxxH, xrgH, xwaH, xkH,
        WTm, WTl, m1p, l2p);
    // 7. r, k0, v (f16 MFMA, dbuf async staging)
    k_gemm<<<dim3(16, 8, 3), 256, 0, stream>>>(
        xrgH, WTq, S4,  xkH, WTk, S6,  xvH, WTv, S7);
    // 8. fused stage-2: dec, kk (normalized), b, k_final
    k_fuse<<<dim3(8, 64), 256, 0, stream>>>(l2p, S6, decay_w2, aaa_w2, ma_w2,
        kkk_w2, mk_w2, tdecay, aaaaa, misc_a, misc_k, S5, S3, S2);
    // 9. WKV7 segmented scan (8 segments of 128 steps):
    //    9a. pass 1: local end-states (z=0) + transition products (z=1)
    k_wkv_p1<<<dim3(7, 32, 2), 1024, 0, stream>>>(S5, S6, S7, S3, S2, Send, Pend);
    //    9b. combine: Sin(g) = Sin(g-1) @ P(g-1) + Send(g-1)
    k_wkv_comb<<<dim3(32), 256, 0, stream>>>(Send, Pend, Sin);
    //    9c. pass 2: replay segments from exact Sin, emit Y
    k_wkv_p2<<<dim3(8, 32), 1024, 0, stream>>>(S4, S5, S6, S7, S3, S2, Sin, S0);
    // 10. groupnorm + bonus + fused gate -> f16 (reuses xxxH slot)
    k_gn<<<dim3(8, 64), 256, 0, stream>>>(S0, S4, S6, S7, l2p, gate_w2,
        faaaa, lnw, lnb, ygH);
    // 11. out = (y*g) @ Wo
    k_gemm<<<dim3(16, 8, 1), 256, 0, stream>>>(
        ygH, WTo, out,  ygH, WTo, out,  ygH, WTo, out);
}

// Round 3
// 524.439 us; speedup vs baseline: 1.1404x; 1.0642x over previous
//
#include <hip/hip_runtime.h>

// RWKV7 attention block, MI355X/gfx950.
// B=1, T=1024, C=2048, H=32, N=64. All inputs/outputs f32.
// Big GEMMs: f16 MFMA 16x16x32, double-buffered global_load_lds(16B) staging.
// LoRA stage-1: MFMA split-K, deterministic per-split partials.
// WKV scan v8: segmented two-pass scan, 4 ROW-STATES PER LANE (wave covers 16
// rows, not 4) -> per-step LDS operand reads shared by 4x more rows (the v7
// kernels were LDS-issue-bound: 16 waves x 6 ds_read_b128 per step for 1.5 KB
// unique data). 4 independent sa-REDUCE16 chains pipeline DPP latency.
//   p1 (merged): 512 thr = 4 S-waves (64 rows, init 0, +vk source) + 4 P-waves
//       (64 rows, init I, vv=0) sharing one d/a/b staging. 224 blocks.
//   comb: Sin(g) = Sin(g-1) @ P(g-1) + Send(g-1), 32 blocks.
//   p2: 256 thr (4 waves x 16 rows), replay from exact Sin, float4 Y stores.
// k_fuse v2: t-tile 16->4 (grid 2048 blocks, 8/CU -> occupancy 20%->~100%;
// it was grid-limited latency-bound at 73us vs ~10us roofline), __logf.

#define T_ 1024
#define C_ 2048
#define H_ 32
#define N_ 64

using half8  = __attribute__((ext_vector_type(8))) _Float16;  // 8 f16 (4 VGPRs)
using half4  = __attribute__((ext_vector_type(4))) _Float16;  // 8 B
using floatx4 = __attribute__((ext_vector_type(4))) float;    // 4 f32 acc

// DPP xor-add within 16-lane rows: quad_perm(0xB1)=xor1, quad_perm(0x4E)=xor2,
// row_half_mirror(0x141)=xor4, row_mirror(0x140)=xor8.
#define DPP_ADD(v, ctrl) \
    ((v) + __int_as_float(__builtin_amdgcn_update_dpp( \
        0, __float_as_int(v), (ctrl), 0xf, 0xf, true)))
#define REDUCE16(v) do { \
    v = DPP_ADD(v, 0xB1); v = DPP_ADD(v, 0x4E); \
    v = DPP_ADD(v, 0x141); v = DPP_ADD(v, 0x140); } while (0)

// async 16B global->LDS (direct-to-LDS DMA; HW dest = wave base + lane*16,
// all call sites construct per-lane lds ptrs matching exactly that layout)
__device__ __forceinline__ void async_cp16(const void* g, void* l) {
    __builtin_amdgcn_global_load_lds(
        (const __attribute__((address_space(1))) void*)g,
        (__attribute__((address_space(3))) void*)l, 16, 0, 0);
}

// ---------------------------------------------------------------------------
// Transpose + convert big weights: W[k][n] f32 -> WT[n][k] f16
// ---------------------------------------------------------------------------
__global__ __launch_bounds__(256) void k_tr(
    const float* __restrict__ W0, const float* __restrict__ W1,
    const float* __restrict__ W2, const float* __restrict__ W3,
    _Float16* __restrict__ D0, _Float16* __restrict__ D1,
    _Float16* __restrict__ D2, _Float16* __restrict__ D3)
{
    const int z = blockIdx.z;
    const float* S = (z == 0) ? W0 : (z == 1) ? W1 : (z == 2) ? W2 : W3;
    _Float16* D = (z == 0) ? D0 : (z == 1) ? D1 : (z == 2) ? D2 : D3;
    const int nb = blockIdx.x * 64, kb = blockIdx.y * 64;
    __shared__ __align__(16) float tile[64][65];
    const int tr = threadIdx.x >> 4, tc4 = (threadIdx.x & 15) * 4;
#pragma unroll
    for (int p = 0; p < 4; ++p) {
        int row = p * 16 + tr;
        float4 v = *(const float4*)&S[(size_t)(kb + row) * C_ + nb + tc4];
        tile[row][tc4 + 0] = v.x; tile[row][tc4 + 1] = v.y;
        tile[row][tc4 + 2] = v.z; tile[row][tc4 + 3] = v.w;
    }
    __syncthreads();
#pragma unroll
    for (int p = 0; p < 4; ++p) {
        int n = p * 16 + tr;
        half4 u;
        u[0] = (_Float16)tile[tc4 + 0][n];
        u[1] = (_Float16)tile[tc4 + 1][n];
        u[2] = (_Float16)tile[tc4 + 2][n];
        u[3] = (_Float16)tile[tc4 + 3][n];
        *(half4*)&D[(size_t)(nb + n) * C_ + kb + tc4] = u;
    }
}

// ---------------------------------------------------------------------------
// Pack+transpose LoRA weights to f16 WT[n][k].
// z=0: WT_m [128][2048] <- maa_w1[2048,128]
// z=1: WT_l [256][2048] <- gate(128) | decay(64) | aaa(16) | ma(16) | kkk(16) | mk(16)
// ---------------------------------------------------------------------------
__global__ __launch_bounds__(256) void k_trW(
    const float* __restrict__ maa_w1, const float* __restrict__ gate_w1,
    const float* __restrict__ decay_w1, const float* __restrict__ aaa_w1,
    const float* __restrict__ ma_w1, const float* __restrict__ kkk_w1,
    const float* __restrict__ mk_w1,
    _Float16* __restrict__ WTm, _Float16* __restrict__ WTl)
{
    const int z = blockIdx.z;
    const int k = blockIdx.x * 256 + threadIdx.x;   // 0..2047
    const int n = blockIdx.y;
    if (z == 0 && n >= 128) return;
    const float* src; int stride, col;
    _Float16* dst;
    if (z == 0) { src = maa_w1; stride = 128; col = n; dst = WTm; }
    else {
        dst = WTl;
        if (n < 128)      { src = gate_w1;  stride = 128; col = n; }
        else if (n < 192) { src = decay_w1; stride = 64;  col = n - 128; }
        else if (n < 208) { src = aaa_w1;   stride = 16;  col = n - 192; }
        else if (n < 224) { src = ma_w1;    stride = 16;  col = n - 208; }
        else if (n < 240) { src = kkk_w1;   stride = 16;  col = n - 224; }
        else              { src = mk_w1;    stride = 16;  col = n - 240; }
    }
    dst[(size_t)n * C_ + k] = (_Float16)src[(size_t)k * stride + col];
}

// ---------------------------------------------------------------------------
// xxxH = f16( x + (x_prev - x) * maa_x )
// ---------------------------------------------------------------------------
__global__ __launch_bounds__(256) void k_prep(
    const float* __restrict__ X, const float* __restrict__ maa_x,
    _Float16* __restrict__ xxxH)
{
    const size_t idx = (size_t)blockIdx.x * 256 + threadIdx.x;
    const int c = (int)(idx & (C_ - 1));
    float cur = X[idx];
    float prev = (idx >= C_) ? X[idx - C_] : 0.0f;
    xxxH[idx] = (_Float16)(cur + (prev - cur) * maa_x[c]);
}

// ---------------------------------------------------------------------------
// LoRA MFMA GEMM, split-K -> per-split partials (deterministic; no atomics).
// BM=64, BN=32, BK=32, ksplit=4.
// which=0: m1p[ks][1024][128] = xxxH @ WTm^T (4 n-tiles)
// which=1: l2p[ks][1024][256], A per n-tile: 0-3 xrg | 4-6 xwa | 7 xk
// ---------------------------------------------------------------------------
__global__ __launch_bounds__(256) void k_lora(
    int which,
    const _Float16* __restrict__ Axxx, const _Float16* __restrict__ Axrg,
    const _Float16* __restrict__ Axwa, const _Float16* __restrict__ Axk,
    const _Float16* __restrict__ WTm, const _Float16* __restrict__ WTl,
    float* __restrict__ m1p, float* __restrict__ l2p)
{
    const int mt = blockIdx.x;      // 16 tiles of 64 rows
    const int nt = blockIdx.y;      // tiles of 32 cols
    const int ks = blockIdx.z;      // 4 K-chunks of 512
    const _Float16* A; const _Float16* BT; float* O; int ostride;
    if (which == 0) { A = Axxx; BT = WTm; O = m1p; ostride = 128; }
    else {
        BT = WTl; O = l2p; ostride = 256;
        A = (nt < 4) ? Axrg : (nt < 7) ? Axwa : Axk;
    }
    O += (size_t)ks * T_ * ostride;
    const int m0 = mt * 64, n0 = nt * 32, k0 = ks * 512;
    const int tid = threadIdx.x;
    __shared__ __align__(16) _Float16 As[64 * 40];
    __shared__ __align__(16) _Float16 Bs[32 * 40];
    const int lane = tid & 63, wv = tid >> 6;
    const int r16 = lane & 15, q = lane >> 4;

    floatx4 acc[2];
    { floatx4 zv = {0.f, 0.f, 0.f, 0.f}; acc[0] = zv; acc[1] = zv; }

    const int arow = tid >> 2, ac8 = (tid & 3) * 8;
    const _Float16* ag = A + (size_t)(m0 + arow) * C_ + k0 + ac8;
    const _Float16* bg = BT + (size_t)(n0 + (tid >> 2)) * C_ + k0 + ac8;

    for (int kc = 0; kc < 512; kc += 32) {
        half8 av = *(const half8*)(ag + kc);
        half8 bv;
        if (tid < 128) bv = *(const half8*)(bg + kc);
        *(half8*)&As[arow * 40 + ac8] = av;
        if (tid < 128) *(half8*)&Bs[(tid >> 2) * 40 + ac8] = bv;
        __syncthreads();
        half8 af = *(const half8*)&As[(wv * 16 + r16) * 40 + q * 8];
        half8 b0 = *(const half8*)&Bs[(r16) * 40 + q * 8];
        half8 b1 = *(const half8*)&Bs[(16 + r16) * 40 + q * 8];
        acc[0] = __builtin_amdgcn_mfma_f32_16x16x32_f16(af, b0, acc[0], 0, 0, 0);
        acc[1] = __builtin_amdgcn_mfma_f32_16x16x32_f16(af, b1, acc[1], 0, 0, 0);
        __syncthreads();
    }
#pragma unroll
    for (int j = 0; j < 2; ++j)
#pragma unroll
        for (int e = 0; e < 4; ++e) {
            int row = m0 + wv * 16 + q * 4 + e;
            int col = n0 + j * 16 + r16;
            O[(size_t)row * ostride + col] = acc[j][e];
        }
}

// ---------------------------------------------------------------------------
// xmix: m1 = sum_ks(m1p), tanh; mix = einsum(m1[T,4,32], maa_w2[4,32,C]);
// emit f16 GEMM operands xrgH/xwaH/xkH/xvH.
// ---------------------------------------------------------------------------
__global__ __launch_bounds__(256) void k_xmix(
    const float* __restrict__ X, const float* __restrict__ m1p,
    const float* __restrict__ w2,
    const float* __restrict__ mrg, const float* __restrict__ mwa,
    const float* __restrict__ mk, const float* __restrict__ mv,
    _Float16* __restrict__ xrgH, _Float16* __restrict__ xwaH,
    _Float16* __restrict__ xkH, _Float16* __restrict__ xvH)
{
    const int tid = threadIdx.x;
    const int c = blockIdx.x * 256 + tid;
    const int t0 = blockIdx.y * 16;
    const size_t P = (size_t)T_ * 128;
    __shared__ __align__(16) float m1s[16][128];
#pragma unroll
    for (int p = 0; p < 2; ++p) {
        int id = tid + p * 256;
        int r = id >> 5, c4 = (id & 31) * 4;
        size_t off = (size_t)(t0 + r) * 128 + c4;
        float4 v0 = *(const float4*)&m1p[off];
        float4 v1 = *(const float4*)&m1p[P + off];
        float4 v2 = *(const float4*)&m1p[2 * P + off];
        float4 v3 = *(const float4*)&m1p[3 * P + off];
        float4 v;
        v.x = tanhf(((v0.x + v1.x) + v2.x) + v3.x);
        v.y = tanhf(((v0.y + v1.y) + v2.y) + v3.y);
        v.z = tanhf(((v0.z + v1.z) + v2.z) + v3.z);
        v.w = tanhf(((v0.w + v1.w) + v2.w) + v3.w);
        *(float4*)&m1s[r][c4] = v;
    }
    __syncthreads();
    float a0[16], a1[16], a2[16], a3[16];
#pragma unroll
    for (int t = 0; t < 16; ++t) { a0[t] = 0.f; a1[t] = 0.f; a2[t] = 0.f; a3[t] = 0.f; }
    for (int d = 0; d < 32; ++d) {
        float w0 = w2[(size_t)(0 * 32 + d) * C_ + c];
        float w1 = w2[(size_t)(1 * 32 + d) * C_ + c];
        float w2v = w2[(size_t)(2 * 32 + d) * C_ + c];
        float w3 = w2[(size_t)(3 * 32 + d) * C_ + c];
#pragma unroll
        for (int t = 0; t < 16; ++t) {
            a0[t] = fmaf(m1s[t][d],      w0,  a0[t]);
            a1[t] = fmaf(m1s[t][32 + d], w1,  a1[t]);
            a2[t] = fmaf(m1s[t][64 + d], w2v, a2[t]);
            a3[t] = fmaf(m1s[t][96 + d], w3,  a3[t]);
        }
    }
    float vrg = mrg[c], vwa = mwa[c], vmk = mk[c], vmv = mv[c];
    float prev = (t0 > 0) ? X[(size_t)(t0 - 1) * C_ + c] : 0.0f;
    for (int t = 0; t < 16; ++t) {
        size_t idx = (size_t)(t0 + t) * C_ + c;
        float cur = X[idx];
        float dx = prev - cur;
        xrgH[idx] = (_Float16)(cur + dx * (vrg + a0[t]));
        xwaH[idx] = (_Float16)(cur + dx * (vwa + a1[t]));
        xkH[idx]  = (_Float16)(cur + dx * (vmk + a2[t]));
        xvH[idx]  = (_Float16)(cur + dx * (vmv + a3[t]));
        prev = cur;
    }
}

// ---------------------------------------------------------------------------
// f16 MFMA GEMM: C[1024,2048] = A(f16) @ W via WT[n][k] f16.
// BM=BN=128, BK=32, 256 thr (4 waves 2x2), 4x4 16x16x32 tiles/wave.
// Double-buffered global_load_lds staging.
// ---------------------------------------------------------------------------
__global__ __launch_bounds__(256) void k_gemm(
    const _Float16* __restrict__ A0, const _Float16* __restrict__ B0, float* __restrict__ C0,
    const _Float16* __restrict__ A1, const _Float16* __restrict__ B1, float* __restrict__ C1,
    const _Float16* __restrict__ A2, const _Float16* __restrict__ B2, float* __restrict__ C2)
{
    const int z = blockIdx.z;
    const _Float16* A = (z == 0) ? A0 : (z == 1) ? A1 : A2;
    const _Float16* Bt = (z == 0) ? B0 : (z == 1) ? B1 : B2;
    float* C = (z == 0) ? C0 : (z == 1) ? C1 : C2;
    const int mtile = blockIdx.y * 128;
    const int ntile = blockIdx.x * 128;
    const int tid = threadIdx.x;
    __shared__ __align__(16) _Float16 As[2][128 * 32];  // unpadded (async layout)
    __shared__ __align__(16) _Float16 Bs[2][128 * 32];
    const int lane = tid & 63;
    const int wvid = tid >> 6;
    const int wm = wvid >> 1, wn = wvid & 1;
    const int r16 = lane & 15, q = lane >> 4;

    floatx4 acc[4][4];
#pragma unroll
    for (int i = 0; i < 4; ++i)
#pragma unroll
        for (int j = 0; j < 4; ++j) { floatx4 zv = {0.f, 0.f, 0.f, 0.f}; acc[i][j] = zv; }

    const int srow = tid >> 2, sq = tid & 3;
    const _Float16* agA = A + (size_t)(mtile + srow) * C_ + sq * 8;
    const _Float16* agB = Bt + (size_t)(ntile + srow) * C_ + sq * 8;
    const int ldso = srow * 32 + sq * 8;
    const size_t rowoff = (size_t)64 * C_;

    async_cp16(agA, &As[0][ldso]);
    async_cp16(agA + rowoff, &As[0][ldso + 64 * 32]);
    async_cp16(agB, &Bs[0][ldso]);
    async_cp16(agB + rowoff, &Bs[0][ldso + 64 * 32]);

    for (int kc = 0; kc < C_; kc += 32) {
        const int p = (kc >> 5) & 1;
        __syncthreads();                      // buf p ready (drains copies)
        if (kc + 32 < C_) {                   // prefetch k+1 into buf p^1
            async_cp16(agA + kc + 32, &As[p ^ 1][ldso]);
            async_cp16(agA + kc + 32 + rowoff, &As[p ^ 1][ldso + 64 * 32]);
            async_cp16(agB + kc + 32, &Bs[p ^ 1][ldso]);
            async_cp16(agB + kc + 32 + rowoff, &Bs[p ^ 1][ldso + 64 * 32]);
        }
        half8 af[4], bf[4];
#pragma unroll
        for (int i = 0; i < 4; ++i)
            af[i] = *(const half8*)&As[p][(wm * 64 + i * 16 + r16) * 32 + q * 8];
#pragma unroll
        for (int j = 0; j < 4; ++j)
            bf[j] = *(const half8*)&Bs[p][(wn * 64 + j * 16 + r16) * 32 + q * 8];
#pragma unroll
        for (int i = 0; i < 4; ++i)
#pragma unroll
            for (int j = 0; j < 4; ++j)
                acc[i][j] = __builtin_amdgcn_mfma_f32_16x16x32_f16(af[i], bf[j], acc[i][j], 0, 0, 0);
    }
    // C/D layout: col = lane&15, row = (lane>>4)*4 + reg
#pragma unroll
    for (int i = 0; i < 4; ++i)
#pragma unroll
        for (int j = 0; j < 4; ++j)
#pragma unroll
            for (int e = 0; e < 4; ++e) {
                int row = mtile + wm * 64 + i * 16 + q * 4 + e;
                int col = ntile + wn * 64 + j * 16 + r16;
                C[(size_t)row * C_ + col] = acc[i][j][e];
            }
}

// ---------------------------------------------------------------------------
// Fused stage-2 v2: dec=exp(w), kk (normalized), b = kk*a, k_final.
// t-tile 4 (grid 8x256 = 2048 blocks -> 8 blocks/CU, was grid-limited at 20%
// occupancy with t-tile 16). l2p partials [4][T][256]: cols 128-191
// decay(tanh) | 192-207 aaa | 208-223 ma | 224-239 kkk(tanh) | 240-255 mk.
// ---------------------------------------------------------------------------
__global__ __launch_bounds__(256) void k_fuse(
    const float* __restrict__ l2p,
    float* __restrict__ K0,
    const float* __restrict__ decay_w2, const float* __restrict__ aaa_w2,
    const float* __restrict__ ma_w2, const float* __restrict__ kkk_w2,
    const float* __restrict__ mk_w2,
    const float* __restrict__ tdecay, const float* __restrict__ aaaaa,
    const float* __restrict__ misc_a, const float* __restrict__ misc_k,
    float* __restrict__ Dout, float* __restrict__ KKout, float* __restrict__ Bout)
{
    const int tid = threadIdx.x;
    const int c = blockIdx.x * 256 + tid;
    const int t0 = blockIdx.y * 4;
    const size_t P = (size_t)T_ * 256;
    __shared__ __align__(16) float wsS[4][96];   // decay64 | aaa16 | ma16
    __shared__ __align__(16) float ksS[4][32];   // kkk16 | mk16
    if (tid < 4 * 24) {
        int r = tid / 24, c4 = (tid % 24) * 4;
        size_t off = (size_t)(t0 + r) * 256 + 128 + c4;
        float4 v0 = *(const float4*)&l2p[off];
        float4 v1 = *(const float4*)&l2p[P + off];
        float4 v2 = *(const float4*)&l2p[2 * P + off];
        float4 v3 = *(const float4*)&l2p[3 * P + off];
        float4 v;
        v.x = ((v0.x + v1.x) + v2.x) + v3.x;
        v.y = ((v0.y + v1.y) + v2.y) + v3.y;
        v.z = ((v0.z + v1.z) + v2.z) + v3.z;
        v.w = ((v0.w + v1.w) + v2.w) + v3.w;
        if (c4 < 64) { v.x = tanhf(v.x); v.y = tanhf(v.y); v.z = tanhf(v.z); v.w = tanhf(v.w); }
        *(float4*)&wsS[r][c4] = v;
    }
    if (tid < 4 * 8) {
        int r = tid / 8, c4 = (tid % 8) * 4;
        size_t off = (size_t)(t0 + r) * 256 + 224 + c4;
        float4 v0 = *(const float4*)&l2p[off];
        float4 v1 = *(const float4*)&l2p[P + off];
        float4 v2 = *(const float4*)&l2p[2 * P + off];
        float4 v3 = *(const float4*)&l2p[3 * P + off];
        float4 v;
        v.x = ((v0.x + v1.x) + v2.x) + v3.x;
        v.y = ((v0.y + v1.y) + v2.y) + v3.y;
        v.z = ((v0.z + v1.z) + v2.z) + v3.z;
        v.w = ((v0.w + v1.w) + v2.w) + v3.w;
        if (c4 < 16) { v.x = tanhf(v.x); v.y = tanhf(v.y); v.z = tanhf(v.z); v.w = tanhf(v.w); }
        *(float4*)&ksS[r][c4] = v;
    }
    __syncthreads();
    float accW[4], accA[4], accMA[4], accKK[4], accMK[4];
#pragma unroll
    for (int r = 0; r < 4; ++r) { accW[r] = 0.f; accA[r] = 0.f; accMA[r] = 0.f; accKK[r] = 0.f; accMK[r] = 0.f; }
    for (int j = 0; j < 64; ++j) {
        float w = decay_w2[(size_t)j * C_ + c];
#pragma unroll
        for (int r = 0; r < 4; ++r) accW[r] = fmaf(wsS[r][j], w, accW[r]);
    }
    for (int j = 0; j < 16; ++j) {
        float wa = aaa_w2[(size_t)j * C_ + c];
        float wm = ma_w2[(size_t)j * C_ + c];
        float wk = kkk_w2[(size_t)j * C_ + c];
        float wq = mk_w2[(size_t)j * C_ + c];
#pragma unroll
        for (int r = 0; r < 4; ++r) {
            accA[r]  = fmaf(wsS[r][64 + j], wa, accA[r]);
            accMA[r] = fmaf(wsS[r][80 + j], wm, accMA[r]);
            accKK[r] = fmaf(ksS[r][j],      wk, accKK[r]);
            accMK[r] = fmaf(ksS[r][16 + j], wq, accMK[r]);
        }
    }
    float td = tdecay[c], aa = aaaaa[c], mia = misc_a[c], mik = misc_k[c];
#pragma unroll
    for (int r = 0; r < 4; ++r) {
        size_t idx = (size_t)(t0 + r) * C_ + c;
        float wraw = td + accW[r];
        float w = -__logf(1.0f + __expf(-wraw)) - 0.5f;   // -softplus(-x) - 0.5
        float a  = 1.0f / (1.0f + __expf(-(aa  + accA[r])));
        float mav = 1.0f / (1.0f + __expf(-(mia + accMA[r])));
        float mkv = 1.0f / (1.0f + __expf(-(mik + accMK[r])));
        float k0 = K0[idx];
        float kkun = k0 + accKK[r];
        float ss = kkun * kkun;
        REDUCE16(ss);
        ss += __shfl_xor(ss, 16, 64);
        ss += __shfl_xor(ss, 32, 64);
        float kn = kkun * (1.0f / fmaxf(sqrtf(ss), 1e-12f));
        Dout[idx]  = __expf(w);                 // dec, precomputed for the scan
        KKout[idx] = kn;
        Bout[idx]  = kn * a;
        K0[idx]    = k0 * (mav + a * (1.0f - mav)) * __expf(fminf(w * mkv, 0.0f));
    }
}

// ---------------------------------------------------------------------------
// WKV7 segmented scan, pass 1 (merged S+P). Grid (7 segs, 32 heads), 512 thr.
// Waves 0-3: S rows (init 0, +v k^T source). Waves 4-7: P rows (init I, no
// source -> vv=0). Each lane carries 4 ROW-STATES (rows row0..row0+3, j-window
// j4..j4+3); per-step d/a/b (+k/v) LDS reads shared by 16 rows per wave.
// ---------------------------------------------------------------------------
__global__ __launch_bounds__(512) void k_wkv_p1(
    const float* __restrict__ DEC, const float* __restrict__ K,
    const float* __restrict__ V, const float* __restrict__ KK,
    const float* __restrict__ Bb,
    float* __restrict__ Send, float* __restrict__ Pend)
{
    const int tid = threadIdx.x;
    const int g = blockIdx.x;                  // segment 0..6
    const int h = blockIdx.y;                  // head
    const int c0 = h * 64;
    const int wv = tid >> 6, lane = tid & 63;
    const int jg = lane & 15, q = lane >> 4, j4 = jg * 4;
    const bool isS = wv < 4;
    const int row0 = (isS ? wv : wv - 4) * 16 + q * 4;   // rows row0..row0+3

    __shared__ __align__(16) float dS[2][16][64], kS[2][16][64], vS[2][16][64],
                                   aS[2][16][64], bS[2][16][64];

    // staging: pos in [0,256) covers one 4KB array-chunk; grp picks arrays.
    // per-wave lds dest = wave-uniform base + lane*16 (DMA constraint holds).
    const int pos = tid & 255, grp = tid >> 8;
    const int pst = pos >> 4, pq4 = (pos & 15) * 4;

#define P1_STAGE(buf, tcb) do {                                               \
    size_t gg = (size_t)((tcb) + pst) * C_ + c0 + pq4;                        \
    if (grp == 0) { async_cp16(&DEC[gg], &dS[buf][pst][pq4]);                 \
                    async_cp16(&KK[gg],  &aS[buf][pst][pq4]);                 \
                    async_cp16(&Bb[gg],  &bS[buf][pst][pq4]); }               \
    else          { async_cp16(&K[gg], &kS[buf][pst][pq4]);                   \
                    async_cp16(&V[gg], &vS[buf][pst][pq4]); }                 \
} while (0)

    float4 s0, s1, s2, s3;
    if (isS) {
        s0 = make_float4(0.f, 0.f, 0.f, 0.f); s1 = s0; s2 = s0; s3 = s0;
    } else {
#define IDROW(m) make_float4((j4 + 0 == row0 + (m)) ? 1.f : 0.f,              \
                             (j4 + 1 == row0 + (m)) ? 1.f : 0.f,              \
                             (j4 + 2 == row0 + (m)) ? 1.f : 0.f,              \
                             (j4 + 3 == row0 + (m)) ? 1.f : 0.f)
        s0 = IDROW(0); s1 = IDROW(1); s2 = IDROW(2); s3 = IDROW(3);
#undef IDROW
    }

    const int t0 = g * 128;
    P1_STAGE(0, t0);

    for (int tc = 0; tc < 128; tc += 16) {
        const int p = (tc >> 4) & 1;
        __syncthreads();                               // buf p ready
        if (tc + 16 < 128) P1_STAGE(p ^ 1, t0 + tc + 16);
#pragma unroll
        for (int tt = 0; tt < 16; ++tt) {
            float4 cd = *(float4*)&dS[p][tt][j4];
            float4 ca = *(float4*)&aS[p][tt][j4];
            float4 cb = *(float4*)&bS[p][tt][j4];
            float4 ck, vv;
            if (isS) {                                 // wave-uniform branch
                ck = *(float4*)&kS[p][tt][j4];
                vv = *(float4*)&vS[p][tt][row0];       // v for rows row0..+3
            } else {
                ck = make_float4(0.f, 0.f, 0.f, 0.f);
                vv = make_float4(0.f, 0.f, 0.f, 0.f);
            }
            float sa0 = -(fmaf(s0.y, ca.y, s0.x * ca.x) + fmaf(s0.w, ca.w, s0.z * ca.z));
            float sa1 = -(fmaf(s1.y, ca.y, s1.x * ca.x) + fmaf(s1.w, ca.w, s1.z * ca.z));
            float sa2 = -(fmaf(s2.y, ca.y, s2.x * ca.x) + fmaf(s2.w, ca.w, s2.z * ca.z));
            float sa3 = -(fmaf(s3.y, ca.y, s3.x * ca.x) + fmaf(s3.w, ca.w, s3.z * ca.z));
            REDUCE16(sa0); REDUCE16(sa1); REDUCE16(sa2); REDUCE16(sa3);
            s0.x = fmaf(s0.x, cd.x, fmaf(sa0, cb.x, vv.x * ck.x));
            s0.y = fmaf(s0.y, cd.y, fmaf(sa0, cb.y, vv.x * ck.y));
            s0.z = fmaf(s0.z, cd.z, fmaf(sa0, cb.z, vv.x * ck.z));
            s0.w = fmaf(s0.w, cd.w, fmaf(sa0, cb.w, vv.x * ck.w));
            s1.x = fmaf(s1.x, cd.x, fmaf(sa1, cb.x, vv.y * ck.x));
            s1.y = fmaf(s1.y, cd.y, fmaf(sa1, cb.y, vv.y * ck.y));
            s1.z = fmaf(s1.z, cd.z, fmaf(sa1, cb.z, vv.y * ck.z));
            s1.w = fmaf(s1.w, cd.w, fmaf(sa1, cb.w, vv.y * ck.w));
            s2.x = fmaf(s2.x, cd.x, fmaf(sa2, cb.x, vv.z * ck.x));
            s2.y = fmaf(s2.y, cd.y, fmaf(sa2, cb.y, vv.z * ck.y));
            s2.z = fmaf(s2.z, cd.z, fmaf(sa2, cb.z, vv.z * ck.z));
            s2.w = fmaf(s2.w, cd.w, fmaf(sa2, cb.w, vv.z * ck.w));
            s3.x = fmaf(s3.x, cd.x, fmaf(sa3, cb.x, vv.w * ck.x));
            s3.y = fmaf(s3.y, cd.y, fmaf(sa3, cb.y, vv.w * ck.y));
            s3.z = fmaf(s3.z, cd.z, fmaf(sa3, cb.z, vv.w * ck.z));
            s3.w = fmaf(s3.w, cd.w, fmaf(sa3, cb.w, vv.w * ck.w));
        }
    }
    float* dst = isS ? Send : Pend;
    size_t base = (size_t)((h * 7 + g) * 64 + row0) * 64 + j4;
    *(float4*)&dst[base +   0] = s0;
    *(float4*)&dst[base +  64] = s1;
    *(float4*)&dst[base + 128] = s2;
    *(float4*)&dst[base + 192] = s3;
#undef P1_STAGE
}

// ---------------------------------------------------------------------------
// WKV7 segmented scan, combine. 32 blocks (1/head) x 256 thr.
// Sin(h,0) = 0; Sin(h,g) = Sin(h,g-1) @ P(h,g-1) + Send(h,g-1), g=1..7.
// Thread t: row i = t>>2, cols jq..jq+15 where jq = (t&3)*16.
// ---------------------------------------------------------------------------
__global__ __launch_bounds__(256) void k_wkv_comb(
    const float* __restrict__ Send, const float* __restrict__ Pend,
    float* __restrict__ Sin)
{
    const int h = blockIdx.x;
    const int tid = threadIdx.x;
    const int i = tid >> 2;
    const int jq = (tid & 3) * 16;
    __shared__ float Sc[64][65];               // padded: Sc[i][k] conflict-free
    __shared__ __align__(16) float Pl[64][64];

    float4 z4 = make_float4(0.f, 0.f, 0.f, 0.f);
#pragma unroll
    for (int c = 0; c < 16; c += 4)
        *(float4*)&Sin[(size_t)(h * 8) * 4096 + (size_t)i * 64 + jq + c] = z4;
#pragma unroll
    for (int c = 0; c < 16; ++c) Sc[i][jq + c] = 0.f;
    __syncthreads();

    for (int g = 1; g < 8; ++g) {
        const float* Pg = &Pend[(size_t)(h * 7 + g - 1) * 4096];
        for (int idx = tid * 4; idx < 4096; idx += 1024) {
            float4 v = *(const float4*)&Pg[idx];
            *(float4*)&Pl[idx >> 6][idx & 63] = v;
        }
        __syncthreads();
        float acc[16];
        const float* Sg = &Send[(size_t)(h * 7 + g - 1) * 4096 + (size_t)i * 64 + jq];
#pragma unroll
        for (int c = 0; c < 16; c += 4) {
            float4 v = *(const float4*)&Sg[c];
            acc[c] = v.x; acc[c + 1] = v.y; acc[c + 2] = v.z; acc[c + 3] = v.w;
        }
        for (int k = 0; k < 64; ++k) {
            float sik = Sc[i][k];
#pragma unroll
            for (int c = 0; c < 16; ++c) acc[c] = fmaf(sik, Pl[k][jq + c], acc[c]);
        }
        __syncthreads();                       // all reads of Sc/Pl done
        float* So = &Sin[(size_t)(h * 8 + g) * 4096 + (size_t)i * 64 + jq];
#pragma unroll
        for (int c = 0; c < 16; ++c) Sc[i][jq + c] = acc[c];
#pragma unroll
        for (int c = 0; c < 16; c += 4) {
            float4 v = make_float4(acc[c], acc[c + 1], acc[c + 2], acc[c + 3]);
            *(float4*)&So[c] = v;
        }
        __syncthreads();                       // Sc updated for next g
    }
}

// ---------------------------------------------------------------------------
// WKV7 segmented scan, pass 2. Grid (8 segs, 32 heads), 256 thr (4 waves x
// 16 rows; 4 row-states per lane). Replay from exact Sin(h,g), emit Y as
// float4 (rows row0..row0+3). Output reductions deferred per 8-step half.
// ---------------------------------------------------------------------------
__global__ __launch_bounds__(256) void k_wkv_p2(
    const float* __restrict__ R, const float* __restrict__ DEC,
    const float* __restrict__ K, const float* __restrict__ V,
    const float* __restrict__ KK, const float* __restrict__ Bb,
    const float* __restrict__ Sin, float* __restrict__ Y)
{
    const int tid = threadIdx.x;
    const int g = blockIdx.x;                  // segment 0..7
    const int h = blockIdx.y;
    const int c0 = h * 64;
    const int wv = tid >> 6, lane = tid & 63;
    const int jg = lane & 15, q = lane >> 4, j4 = jg * 4;
    const int row0 = wv * 16 + q * 4;          // rows row0..row0+3

    __shared__ __align__(16) float rS[2][16][64], dS[2][16][64], kS[2][16][64],
                                   aS[2][16][64], bS[2][16][64], vS[2][16][64];

    const int pst = tid >> 4, pq4 = (tid & 15) * 4;

#define P2_STAGE(buf, tcb) do {                                               \
    size_t gg = (size_t)((tcb) + pst) * C_ + c0 + pq4;                        \
    async_cp16(&R[gg],   &rS[buf][pst][pq4]);                                 \
    async_cp16(&DEC[gg], &dS[buf][pst][pq4]);                                 \
    async_cp16(&K[gg],   &kS[buf][pst][pq4]);                                 \
    async_cp16(&V[gg],   &vS[buf][pst][pq4]);                                 \
    async_cp16(&KK[gg],  &aS[buf][pst][pq4]);                                 \
    async_cp16(&Bb[gg],  &bS[buf][pst][pq4]);                                 \
} while (0)

    float4 s0, s1, s2, s3;
    {
        const float* Sb = &Sin[(size_t)((h * 8 + g) * 64 + row0) * 64 + j4];
        s0 = *(const float4*)&Sb[0];
        s1 = *(const float4*)&Sb[64];
        s2 = *(const float4*)&Sb[128];
        s3 = *(const float4*)&Sb[192];
    }

    const int t0 = g * 128;
    P2_STAGE(0, t0);

    for (int tc = 0; tc < 128; tc += 16) {
        const int p = (tc >> 4) & 1;
        __syncthreads();                               // buf p ready
        if (tc + 16 < 128) P2_STAGE(p ^ 1, t0 + tc + 16);
#pragma unroll
        for (int hh = 0; hh < 2; ++hh) {
            float po0[8], po1[8], po2[8], po3[8];
#pragma unroll
            for (int qs = 0; qs < 8; ++qs) {
                const int tt = hh * 8 + qs;
                float4 cr = *(float4*)&rS[p][tt][j4];
                float4 cd = *(float4*)&dS[p][tt][j4];
                float4 ck = *(float4*)&kS[p][tt][j4];
                float4 ca = *(float4*)&aS[p][tt][j4];
                float4 cb = *(float4*)&bS[p][tt][j4];
                float4 vv = *(float4*)&vS[p][tt][row0];
                float sa0 = -(fmaf(s0.y, ca.y, s0.x * ca.x) + fmaf(s0.w, ca.w, s0.z * ca.z));
                float sa1 = -(fmaf(s1.y, ca.y, s1.x * ca.x) + fmaf(s1.w, ca.w, s1.z * ca.z));
                float sa2 = -(fmaf(s2.y, ca.y, s2.x * ca.x) + fmaf(s2.w, ca.w, s2.z * ca.z));
                float sa3 = -(fmaf(s3.y, ca.y, s3.x * ca.x) + fmaf(s3.w, ca.w, s3.z * ca.z));
                REDUCE16(sa0); REDUCE16(sa1); REDUCE16(sa2); REDUCE16(sa3);
                s0.x = fmaf(s0.x, cd.x, fmaf(sa0, cb.x, vv.x * ck.x));
                s0.y = fmaf(s0.y, cd.y, fmaf(sa0, cb.y, vv.x * ck.y));
                s0.z = fmaf(s0.z, cd.z, fmaf(sa0, cb.z, vv.x * ck.z));
                s0.w = fmaf(s0.w, cd.w, fmaf(sa0, cb.w, vv.x * ck.w));
                s1.x = fmaf(s1.x, cd.x, fmaf(sa1, cb.x, vv.y * ck.x));
                s1.y = fmaf(s1.y, cd.y, fmaf(sa1, cb.y, vv.y * ck.y));
                s1.z = fmaf(s1.z, cd.z, fmaf(sa1, cb.z, vv.y * ck.z));
                s1.w = fmaf(s1.w, cd.w, fmaf(sa1, cb.w, vv.y * ck.w));
                s2.x = fmaf(s2.x, cd.x, fmaf(sa2, cb.x, vv.z * ck.x));
                s2.y = fmaf(s2.y, cd.y, fmaf(sa2, cb.y, vv.z * ck.y));
                s2.z = fmaf(s2.z, cd.z, fmaf(sa2, cb.z, vv.z * ck.z));
                s2.w = fmaf(s2.w, cd.w, fmaf(sa2, cb.w, vv.z * ck.w));
                s3.x = fmaf(s3.x, cd.x, fmaf(sa3, cb.x, vv.w * ck.x));
                s3.y = fmaf(s3.y, cd.y, fmaf(sa3, cb.y, vv.w * ck.y));
                s3.z = fmaf(s3.z, cd.z, fmaf(sa3, cb.z, vv.w * ck.z));
                s3.w = fmaf(s3.w, cd.w, fmaf(sa3, cb.w, vv.w * ck.w));
                po0[qs] = fmaf(s0.w, cr.w, fmaf(s0.z, cr.z, fmaf(s0.y, cr.y, s0.x * cr.x)));
                po1[qs] = fmaf(s1.w, cr.w, fmaf(s1.z, cr.z, fmaf(s1.y, cr.y, s1.x * cr.x)));
                po2[qs] = fmaf(s2.w, cr.w, fmaf(s2.z, cr.z, fmaf(s2.y, cr.y, s2.x * cr.x)));
                po3[qs] = fmaf(s3.w, cr.w, fmaf(s3.z, cr.z, fmaf(s3.y, cr.y, s3.x * cr.x)));
            }
            // deferred: 32 independent DPP butterflies pipeline
#pragma unroll
            for (int qs = 0; qs < 8; ++qs) {
                REDUCE16(po0[qs]); REDUCE16(po1[qs]);
                REDUCE16(po2[qs]); REDUCE16(po3[qs]);
            }
            if (jg == 0) {
#pragma unroll
                for (int qs = 0; qs < 8; ++qs) {
                    float4 o = make_float4(po0[qs], po1[qs], po2[qs], po3[qs]);
                    *(float4*)&Y[(size_t)(t0 + tc + hh * 8 + qs) * C_ + c0 + row0] = o;
                }
            }
        }
    }
#undef P2_STAGE
}

// ---------------------------------------------------------------------------
// GroupNorm + bonus + fused gate, t-tiled (16 t/block so the 128 gw2 loads
// amortize): YG = f16((gn(y) + bonus) * (tanh(l2 sum) @ gate_w2)).
// ---------------------------------------------------------------------------
__global__ __launch_bounds__(256) void k_gn(
    const float* __restrict__ Y, const float* __restrict__ R, const float* __restrict__ K,
    const float* __restrict__ V, const float* __restrict__ l2p,
    const float* __restrict__ gw2,
    const float* __restrict__ faaaa, const float* __restrict__ lnw,
    const float* __restrict__ lnb, _Float16* __restrict__ YG)
{
    const int tid = threadIdx.x;
    const int c = blockIdx.x * 256 + tid;
    const int t0 = blockIdx.y * 16;
    const size_t P = (size_t)T_ * 256;
    __shared__ __align__(16) float gs[16][128];
    for (int id = tid; id < 16 * 128; id += 256) {
        int r = id >> 7, cc = id & 127;
        size_t off = (size_t)(t0 + r) * 256 + cc;
        float v = ((l2p[off] + l2p[P + off]) + l2p[2 * P + off]) + l2p[3 * P + off];
        gs[r][cc] = tanhf(v);
    }
    __syncthreads();
    float gacc[16];
#pragma unroll
    for (int r = 0; r < 16; ++r) gacc[r] = 0.f;
    for (int j = 0; j < 128; ++j) {
        float w = gw2[(size_t)j * C_ + c];
#pragma unroll
        for (int r = 0; r < 16; ++r) gacc[r] = fmaf(gs[r][j], w, gacc[r]);
    }
    float fa = faaaa[c], lw = lnw[c], lb = lnb[c];
    for (int r = 0; r < 16; ++r) {
        const size_t idx = (size_t)(t0 + r) * C_ + c;
        float y = Y[idx];
        float s1 = y, s2 = y * y;
#pragma unroll
        for (int off = 1; off < 64; off <<= 1) {
            s1 += __shfl_xor(s1, off, 64);
            s2 += __shfl_xor(s2, off, 64);
        }
        float mu = s1 * (1.0f / 64.0f);
        float var = s2 * (1.0f / 64.0f) - mu * mu;
        float gn = (y - mu) * rsqrtf(var + 0.00064f) * lw + lb;
        float p = R[idx] * K[idx] * fa;
#pragma unroll
        for (int off = 1; off < 64; off <<= 1) p += __shfl_xor(p, off, 64);
        float y2 = gn + p * V[idx];
        YG[idx] = (_Float16)(y2 * gacc[r]);
    }
}

// ---------------------------------------------------------------------------
extern "C" void kernel_launch(void* const* d_in, const int* in_sizes, int n_in,
                              void* d_out, int out_size, void* d_ws, size_t ws_size,
                              hipStream_t stream)
{
    (void)in_sizes; (void)n_in; (void)out_size; (void)ws_size;
    const float* hidden   = (const float*)d_in[0];
    const float* Wq       = (const float*)d_in[1];
    const float* Wk       = (const float*)d_in[2];
    const float* Wv       = (const float*)d_in[3];
    const float* Wo       = (const float*)d_in[4];
    const float* maa_x    = (const float*)d_in[5];
    const float* maa_rg   = (const float*)d_in[6];
    const float* maa_wa   = (const float*)d_in[7];
    const float* maa_k    = (const float*)d_in[8];
    const float* maa_v    = (const float*)d_in[9];
    const float* maa_w1   = (const float*)d_in[10];
    const float* maa_w2   = (const float*)d_in[11];
    const float* tdecay   = (const float*)d_in[12];
    const float* decay_w1 = (const float*)d_in[13];
    const float* decay_w2 = (const float*)d_in[14];
    const float* aaaaa    = (const float*)d_in[15];
    const float* aaa_w1   = (const float*)d_in[16];
    const float* aaa_w2   = (const float*)d_in[17];
    const float* kkk_w1   = (const float*)d_in[18];
    const float* kkk_w2   = (const float*)d_in[19];
    const float* gate_w1  = (const float*)d_in[20];
    const float* gate_w2  = (const float*)d_in[21];
    const float* misc_a   = (const float*)d_in[22];
    const float* ma_w1    = (const float*)d_in[23];
    const float* ma_w2    = (const float*)d_in[24];
    const float* misc_k   = (const float*)d_in[25];
    const float* mk_w1    = (const float*)d_in[26];
    const float* mk_w2    = (const float*)d_in[27];
    const float* faaaa    = (const float*)d_in[28];
    const float* lnw      = (const float*)d_in[29];
    const float* lnb      = (const float*)d_in[30];

    float* ws = (float*)d_ws;
    const size_t TC = (size_t)T_ * C_;
    // f32 buffers:
    //   S0: y   S2: b   S3: kk   S4: r   S5: dec   S6: k0 -> k   S7: v
    //   S1 slot (8MB) repurposed: Send [32][7][64][64] + Pend [32][7][64][64]
    float* S0 = ws + 0 * TC;
    float* Send = ws + 1 * TC;                   // 917504 floats
    float* Pend = Send + (size_t)32 * 7 * 64 * 64;
    float* S2 = ws + 2 * TC;
    float* S3 = ws + 3 * TC;
    float* S4 = ws + 4 * TC;
    float* S5 = ws + 5 * TC;
    float* S6 = ws + 6 * TC;
    float* S7 = ws + 7 * TC;
    float* m1p = ws + 8 * TC;                    // [4][T][128] partials
    float* l2p = m1p + (size_t)4 * T_ * 128;     // [4][T][256] partials
    // f16 region
    _Float16* WTq = (_Float16*)(l2p + (size_t)4 * T_ * 256);
    _Float16* WTk = WTq + (size_t)C_ * C_;
    _Float16* WTv = WTk + (size_t)C_ * C_;
    _Float16* WTo = WTv + (size_t)C_ * C_;
    _Float16* WTm = WTo + (size_t)C_ * C_;       // [128,2048]
    _Float16* WTl = WTm + (size_t)128 * C_;      // [256,2048]
    _Float16* xxxH = WTl + (size_t)256 * C_;
    _Float16* xrgH = xxxH + TC;
    _Float16* xwaH = xrgH + TC;
    _Float16* xkH  = xwaH + TC;
    _Float16* xvH  = xkH + TC;
    _Float16* ygH  = xxxH;                       // xxxH dead after step 6
    // xrgH dead after step 7 -> reuse its 4MB as Sin [32][8][64][64] f32
    float* Sin = (float*)xrgH;
    float* out = (float*)d_out;

    // 1. transpose+convert big weights
    k_tr<<<dim3(32, 32, 4), 256, 0, stream>>>(Wq, Wk, Wv, Wo, WTq, WTk, WTv, WTo);
    // 2. pack+transpose LoRA weights (z=0: WTm, z=1: WTl)
    k_trW<<<dim3(8, 256, 2), 256, 0, stream>>>(maa_w1, gate_w1, decay_w1,
        aaa_w1, ma_w1, kkk_w1, mk_w1, WTm, WTl);
    // 3. xxxH
    k_prep<<<dim3((int)(TC / 256)), 256, 0, stream>>>(hidden, maa_x, xxxH);
    // 4. m1 partials = xxxH @ WTm^T
    k_lora<<<dim3(16, 4, 4), 256, 0, stream>>>(0, xxxH, xxxH, xxxH, xxxH,
        WTm, WTl, m1p, l2p);
    // 5. xmix -> f16 operands
    k_xmix<<<dim3(8, 64), 256, 0, stream>>>(hidden, m1p, maa_w2,
        maa_rg, maa_wa, maa_k, maa_v, xrgH, xwaH, xkH, xvH);
    // 6. l2 partials (gate | decay | aaa | ma | kkk | mk)
    k_lora<<<dim3(16, 8, 4), 256, 0, stream>>>(1, xxxH, xrgH, xwaH, xkH,
        WTm, WTl, m1p, l2p);
    // 7. r, k0, v (f16 MFMA, dbuf async staging)
    k_gemm<<<dim3(16, 8, 3), 256, 0, stream>>>(
        xrgH, WTq, S4,  xkH, WTk, S6,  xvH, WTv, S7);
    // 8. fused stage-2: dec, kk (normalized), b, k_final (t-tile 4)
    k_fuse<<<dim3(8, 256), 256, 0, stream>>>(l2p, S6, decay_w2, aaa_w2, ma_w2,
        kkk_w2, mk_w2, tdecay, aaaaa, misc_a, misc_k, S5, S3, S2);
    // 9. WKV7 segmented scan (8 segments of 128 steps):
    //    9a. pass 1 (merged): local end-states + transition products
    k_wkv_p1<<<dim3(7, 32), 512, 0, stream>>>(S5, S6, S7, S3, S2, Send, Pend);
    //    9b. combine: Sin(g) = Sin(g-1) @ P(g-1) + Send(g-1)
    k_wkv_comb<<<dim3(32), 256, 0, stream>>>(Send, Pend, Sin);
    //    9c. pass 2: replay segments from exact Sin, emit Y
    k_wkv_p2<<<dim3(8, 32), 256, 0, stream>>>(S4, S5, S6, S7, S3, S2, Sin, S0);
    // 10. groupnorm + bonus + fused gate -> f16 (reuses xxxH slot)
    k_gn<<<dim3(8, 64), 256, 0, stream>>>(S0, S4, S6, S7, l2p, gate_w2,
        faaaa, lnw, lnb, ygH);
    // 11. out = (y*g) @ Wo
    k_gemm<<<dim3(16, 8, 1), 256, 0, stream>>>(
        ygH, WTo, out,  ygH, WTo, out,  ygH, WTo, out);
}

// Round 4
// 513.159 us; speedup vs baseline: 1.1655x; 1.0220x over previous
//
#include <hip/hip_runtime.h>

// RWKV7 attention block, MI355X/gfx950.
// B=1, T=1024, C=2048, H=32, N=64. All inputs/outputs f32.
// Big GEMMs v2: f16 MFMA 16x16x32, BM=128 BN=64 BK=32 (grid 768 blocks for the
// triple GEMM -> 3 blocks/CU; was 384 = 1.5/CU, 13% occupancy, every latency
// exposed). LDS slot-XOR swizzle (slot ^= (row>>1)&3, inverse applied on the
// global_load_lds SOURCE, same XOR on ds_read) -> uniform 8/bank b128 reads
// (was ~4-way conflicts, 3.1M conflict cycles/dispatch).
// LoRA stage-1: MFMA split-K, deterministic per-split partials.
// WKV scan v8: segmented two-pass (exact linear recurrence), 4 row-states/lane.
// k_fuse v2: t-tile 4, 2048 blocks.

#define T_ 1024
#define C_ 2048
#define H_ 32
#define N_ 64

using half8  = __attribute__((ext_vector_type(8))) _Float16;  // 8 f16 (4 VGPRs)
using half4  = __attribute__((ext_vector_type(4))) _Float16;  // 8 B
using floatx4 = __attribute__((ext_vector_type(4))) float;    // 4 f32 acc

// DPP xor-add within 16-lane rows: quad_perm(0xB1)=xor1, quad_perm(0x4E)=xor2,
// row_half_mirror(0x141)=xor4, row_mirror(0x140)=xor8.
#define DPP_ADD(v, ctrl) \
    ((v) + __int_as_float(__builtin_amdgcn_update_dpp( \
        0, __float_as_int(v), (ctrl), 0xf, 0xf, true)))
#define REDUCE16(v) do { \
    v = DPP_ADD(v, 0xB1); v = DPP_ADD(v, 0x4E); \
    v = DPP_ADD(v, 0x141); v = DPP_ADD(v, 0x140); } while (0)

// async 16B global->LDS (direct-to-LDS DMA; HW dest = wave base + lane*16,
// all call sites construct per-lane lds ptrs matching exactly that layout)
__device__ __forceinline__ void async_cp16(const void* g, void* l) {
    __builtin_amdgcn_global_load_lds(
        (const __attribute__((address_space(1))) void*)g,
        (__attribute__((address_space(3))) void*)l, 16, 0, 0);
}

// ---------------------------------------------------------------------------
// Transpose + convert big weights: W[k][n] f32 -> WT[n][k] f16
// ---------------------------------------------------------------------------
__global__ __launch_bounds__(256) void k_tr(
    const float* __restrict__ W0, const float* __restrict__ W1,
    const float* __restrict__ W2, const float* __restrict__ W3,
    _Float16* __restrict__ D0, _Float16* __restrict__ D1,
    _Float16* __restrict__ D2, _Float16* __restrict__ D3)
{
    const int z = blockIdx.z;
    const float* S = (z == 0) ? W0 : (z == 1) ? W1 : (z == 2) ? W2 : W3;
    _Float16* D = (z == 0) ? D0 : (z == 1) ? D1 : (z == 2) ? D2 : D3;
    const int nb = blockIdx.x * 64, kb = blockIdx.y * 64;
    __shared__ __align__(16) float tile[64][65];
    const int tr = threadIdx.x >> 4, tc4 = (threadIdx.x & 15) * 4;
#pragma unroll
    for (int p = 0; p < 4; ++p) {
        int row = p * 16 + tr;
        float4 v = *(const float4*)&S[(size_t)(kb + row) * C_ + nb + tc4];
        tile[row][tc4 + 0] = v.x; tile[row][tc4 + 1] = v.y;
        tile[row][tc4 + 2] = v.z; tile[row][tc4 + 3] = v.w;
    }
    __syncthreads();
#pragma unroll
    for (int p = 0; p < 4; ++p) {
        int n = p * 16 + tr;
        half4 u;
        u[0] = (_Float16)tile[tc4 + 0][n];
        u[1] = (_Float16)tile[tc4 + 1][n];
        u[2] = (_Float16)tile[tc4 + 2][n];
        u[3] = (_Float16)tile[tc4 + 3][n];
        *(half4*)&D[(size_t)(nb + n) * C_ + kb + tc4] = u;
    }
}

// ---------------------------------------------------------------------------
// Pack+transpose LoRA weights to f16 WT[n][k].
// z=0: WT_m [128][2048] <- maa_w1[2048,128]
// z=1: WT_l [256][2048] <- gate(128) | decay(64) | aaa(16) | ma(16) | kkk(16) | mk(16)
// ---------------------------------------------------------------------------
__global__ __launch_bounds__(256) void k_trW(
    const float* __restrict__ maa_w1, const float* __restrict__ gate_w1,
    const float* __restrict__ decay_w1, const float* __restrict__ aaa_w1,
    const float* __restrict__ ma_w1, const float* __restrict__ kkk_w1,
    const float* __restrict__ mk_w1,
    _Float16* __restrict__ WTm, _Float16* __restrict__ WTl)
{
    const int z = blockIdx.z;
    const int k = blockIdx.x * 256 + threadIdx.x;   // 0..2047
    const int n = blockIdx.y;
    if (z == 0 && n >= 128) return;
    const float* src; int stride, col;
    _Float16* dst;
    if (z == 0) { src = maa_w1; stride = 128; col = n; dst = WTm; }
    else {
        dst = WTl;
        if (n < 128)      { src = gate_w1;  stride = 128; col = n; }
        else if (n < 192) { src = decay_w1; stride = 64;  col = n - 128; }
        else if (n < 208) { src = aaa_w1;   stride = 16;  col = n - 192; }
        else if (n < 224) { src = ma_w1;    stride = 16;  col = n - 208; }
        else if (n < 240) { src = kkk_w1;   stride = 16;  col = n - 224; }
        else              { src = mk_w1;    stride = 16;  col = n - 240; }
    }
    dst[(size_t)n * C_ + k] = (_Float16)src[(size_t)k * stride + col];
}

// ---------------------------------------------------------------------------
// xxxH = f16( x + (x_prev - x) * maa_x )
// ---------------------------------------------------------------------------
__global__ __launch_bounds__(256) void k_prep(
    const float* __restrict__ X, const float* __restrict__ maa_x,
    _Float16* __restrict__ xxxH)
{
    const size_t idx = (size_t)blockIdx.x * 256 + threadIdx.x;
    const int c = (int)(idx & (C_ - 1));
    float cur = X[idx];
    float prev = (idx >= C_) ? X[idx - C_] : 0.0f;
    xxxH[idx] = (_Float16)(cur + (prev - cur) * maa_x[c]);
}

// ---------------------------------------------------------------------------
// LoRA MFMA GEMM, split-K -> per-split partials (deterministic; no atomics).
// BM=64, BN=32, BK=32, ksplit=4.
// which=0: m1p[ks][1024][128] = xxxH @ WTm^T (4 n-tiles)
// which=1: l2p[ks][1024][256], A per n-tile: 0-3 xrg | 4-6 xwa | 7 xk
// ---------------------------------------------------------------------------
__global__ __launch_bounds__(256) void k_lora(
    int which,
    const _Float16* __restrict__ Axxx, const _Float16* __restrict__ Axrg,
    const _Float16* __restrict__ Axwa, const _Float16* __restrict__ Axk,
    const _Float16* __restrict__ WTm, const _Float16* __restrict__ WTl,
    float* __restrict__ m1p, float* __restrict__ l2p)
{
    const int mt = blockIdx.x;      // 16 tiles of 64 rows
    const int nt = blockIdx.y;      // tiles of 32 cols
    const int ks = blockIdx.z;      // 4 K-chunks of 512
    const _Float16* A; const _Float16* BT; float* O; int ostride;
    if (which == 0) { A = Axxx; BT = WTm; O = m1p; ostride = 128; }
    else {
        BT = WTl; O = l2p; ostride = 256;
        A = (nt < 4) ? Axrg : (nt < 7) ? Axwa : Axk;
    }
    O += (size_t)ks * T_ * ostride;
    const int m0 = mt * 64, n0 = nt * 32, k0 = ks * 512;
    const int tid = threadIdx.x;
    __shared__ __align__(16) _Float16 As[64 * 40];
    __shared__ __align__(16) _Float16 Bs[32 * 40];
    const int lane = tid & 63, wv = tid >> 6;
    const int r16 = lane & 15, q = lane >> 4;

    floatx4 acc[2];
    { floatx4 zv = {0.f, 0.f, 0.f, 0.f}; acc[0] = zv; acc[1] = zv; }

    const int arow = tid >> 2, ac8 = (tid & 3) * 8;
    const _Float16* ag = A + (size_t)(m0 + arow) * C_ + k0 + ac8;
    const _Float16* bg = BT + (size_t)(n0 + (tid >> 2)) * C_ + k0 + ac8;

    for (int kc = 0; kc < 512; kc += 32) {
        half8 av = *(const half8*)(ag + kc);
        half8 bv;
        if (tid < 128) bv = *(const half8*)(bg + kc);
        *(half8*)&As[arow * 40 + ac8] = av;
        if (tid < 128) *(half8*)&Bs[(tid >> 2) * 40 + ac8] = bv;
        __syncthreads();
        half8 af = *(const half8*)&As[(wv * 16 + r16) * 40 + q * 8];
        half8 b0 = *(const half8*)&Bs[(r16) * 40 + q * 8];
        half8 b1 = *(const half8*)&Bs[(16 + r16) * 40 + q * 8];
        acc[0] = __builtin_amdgcn_mfma_f32_16x16x32_f16(af, b0, acc[0], 0, 0, 0);
        acc[1] = __builtin_amdgcn_mfma_f32_16x16x32_f16(af, b1, acc[1], 0, 0, 0);
        __syncthreads();
    }
#pragma unroll
    for (int j = 0; j < 2; ++j)
#pragma unroll
        for (int e = 0; e < 4; ++e) {
            int row = m0 + wv * 16 + q * 4 + e;
            int col = n0 + j * 16 + r16;
            O[(size_t)row * ostride + col] = acc[j][e];
        }
}

// ---------------------------------------------------------------------------
// xmix: m1 = sum_ks(m1p), tanh; mix = einsum(m1[T,4,32], maa_w2[4,32,C]);
// emit f16 GEMM operands xrgH/xwaH/xkH/xvH.
// ---------------------------------------------------------------------------
__global__ __launch_bounds__(256) void k_xmix(
    const float* __restrict__ X, const float* __restrict__ m1p,
    const float* __restrict__ w2,
    const float* __restrict__ mrg, const float* __restrict__ mwa,
    const float* __restrict__ mk, const float* __restrict__ mv,
    _Float16* __restrict__ xrgH, _Float16* __restrict__ xwaH,
    _Float16* __restrict__ xkH, _Float16* __restrict__ xvH)
{
    const int tid = threadIdx.x;
    const int c = blockIdx.x * 256 + tid;
    const int t0 = blockIdx.y * 16;
    const size_t P = (size_t)T_ * 128;
    __shared__ __align__(16) float m1s[16][128];
#pragma unroll
    for (int p = 0; p < 2; ++p) {
        int id = tid + p * 256;
        int r = id >> 5, c4 = (id & 31) * 4;
        size_t off = (size_t)(t0 + r) * 128 + c4;
        float4 v0 = *(const float4*)&m1p[off];
        float4 v1 = *(const float4*)&m1p[P + off];
        float4 v2 = *(const float4*)&m1p[2 * P + off];
        float4 v3 = *(const float4*)&m1p[3 * P + off];
        float4 v;
        v.x = tanhf(((v0.x + v1.x) + v2.x) + v3.x);
        v.y = tanhf(((v0.y + v1.y) + v2.y) + v3.y);
        v.z = tanhf(((v0.z + v1.z) + v2.z) + v3.z);
        v.w = tanhf(((v0.w + v1.w) + v2.w) + v3.w);
        *(float4*)&m1s[r][c4] = v;
    }
    __syncthreads();
    float a0[16], a1[16], a2[16], a3[16];
#pragma unroll
    for (int t = 0; t < 16; ++t) { a0[t] = 0.f; a1[t] = 0.f; a2[t] = 0.f; a3[t] = 0.f; }
    for (int d = 0; d < 32; ++d) {
        float w0 = w2[(size_t)(0 * 32 + d) * C_ + c];
        float w1 = w2[(size_t)(1 * 32 + d) * C_ + c];
        float w2v = w2[(size_t)(2 * 32 + d) * C_ + c];
        float w3 = w2[(size_t)(3 * 32 + d) * C_ + c];
#pragma unroll
        for (int t = 0; t < 16; ++t) {
            a0[t] = fmaf(m1s[t][d],      w0,  a0[t]);
            a1[t] = fmaf(m1s[t][32 + d], w1,  a1[t]);
            a2[t] = fmaf(m1s[t][64 + d], w2v, a2[t]);
            a3[t] = fmaf(m1s[t][96 + d], w3,  a3[t]);
        }
    }
    float vrg = mrg[c], vwa = mwa[c], vmk = mk[c], vmv = mv[c];
    float prev = (t0 > 0) ? X[(size_t)(t0 - 1) * C_ + c] : 0.0f;
    for (int t = 0; t < 16; ++t) {
        size_t idx = (size_t)(t0 + t) * C_ + c;
        float cur = X[idx];
        float dx = prev - cur;
        xrgH[idx] = (_Float16)(cur + dx * (vrg + a0[t]));
        xwaH[idx] = (_Float16)(cur + dx * (vwa + a1[t]));
        xkH[idx]  = (_Float16)(cur + dx * (vmk + a2[t]));
        xvH[idx]  = (_Float16)(cur + dx * (vmv + a3[t]));
        prev = cur;
    }
}

// ---------------------------------------------------------------------------
// f16 MFMA GEMM v2: C[1024,2048] = A(f16) @ W via WT[n][k] f16.
// BM=128, BN=64, BK=32, 256 thr (4 waves 2x2), 4x2 16x16x32 tiles/wave.
// Grid 32x8(xz): 768 blocks for z=3 (3 blocks/CU; v1 had 384 = 1.5/CU).
// LDS slot-XOR swizzle: LDS slot u of row r holds global K-slot u ^ ((r>>1)&3)
// (applied on the global_load_lds SOURCE address; dest stays linear per DMA
// constraint). Reads XOR the same -> uniform 8/bank (conflict-free b128).
// ---------------------------------------------------------------------------
__global__ __launch_bounds__(256) void k_gemm(
    const _Float16* __restrict__ A0, const _Float16* __restrict__ B0, float* __restrict__ C0,
    const _Float16* __restrict__ A1, const _Float16* __restrict__ B1, float* __restrict__ C1,
    const _Float16* __restrict__ A2, const _Float16* __restrict__ B2, float* __restrict__ C2)
{
    const int z = blockIdx.z;
    const _Float16* A = (z == 0) ? A0 : (z == 1) ? A1 : A2;
    const _Float16* Bt = (z == 0) ? B0 : (z == 1) ? B1 : B2;
    float* C = (z == 0) ? C0 : (z == 1) ? C1 : C2;
    const int mtile = blockIdx.y * 128;
    const int ntile = blockIdx.x * 64;
    const int tid = threadIdx.x;
    __shared__ __align__(16) _Float16 As[2][128 * 32];
    __shared__ __align__(16) _Float16 Bs[2][64 * 32];
    const int lane = tid & 63;
    const int wvid = tid >> 6;
    const int wm = wvid >> 1, wn = wvid & 1;
    const int r16 = lane & 15, q = lane >> 4;
    // read-side swizzled slot offset (halfwords). (row>>1)&3 == (r16>>1)&3 for
    // every fragment row (wm*64, i*16, wn*32, j*16 all vanish in bits 1..2).
    const int qs = (q ^ ((r16 >> 1) & 3)) * 8;

    floatx4 acc[4][2];
#pragma unroll
    for (int i = 0; i < 4; ++i)
#pragma unroll
        for (int j = 0; j < 2; ++j) { floatx4 zv = {0.f, 0.f, 0.f, 0.f}; acc[i][j] = zv; }

    const int srow = tid >> 2, sq = tid & 3;
    const int sqg = (sq ^ ((srow >> 1) & 3)) * 8;   // inverse swizzle on source
    const _Float16* agA = A + (size_t)(mtile + srow) * C_ + sqg;
    const _Float16* agB = Bt + (size_t)(ntile + srow) * C_ + sqg;
    const int ldso = srow * 32 + sq * 8;            // linear DMA dest (tid*16B)
    const size_t rowoff = (size_t)64 * C_;          // (srow+64): same swizzle

    async_cp16(agA, &As[0][ldso]);
    async_cp16(agA + rowoff, &As[0][ldso + 64 * 32]);
    async_cp16(agB, &Bs[0][ldso]);

    for (int kc = 0; kc < C_; kc += 32) {
        const int p = (kc >> 5) & 1;
        __syncthreads();                      // buf p ready (drains copies)
        if (kc + 32 < C_) {                   // prefetch k+1 into buf p^1
            async_cp16(agA + kc + 32, &As[p ^ 1][ldso]);
            async_cp16(agA + kc + 32 + rowoff, &As[p ^ 1][ldso + 64 * 32]);
            async_cp16(agB + kc + 32, &Bs[p ^ 1][ldso]);
        }
        half8 af[4], bf[2];
#pragma unroll
        for (int i = 0; i < 4; ++i)
            af[i] = *(const half8*)&As[p][(wm * 64 + i * 16 + r16) * 32 + qs];
#pragma unroll
        for (int j = 0; j < 2; ++j)
            bf[j] = *(const half8*)&Bs[p][(wn * 32 + j * 16 + r16) * 32 + qs];
#pragma unroll
        for (int i = 0; i < 4; ++i)
#pragma unroll
            for (int j = 0; j < 2; ++j)
                acc[i][j] = __builtin_amdgcn_mfma_f32_16x16x32_f16(af[i], bf[j], acc[i][j], 0, 0, 0);
    }
    // C/D layout: col = lane&15, row = (lane>>4)*4 + reg
#pragma unroll
    for (int i = 0; i < 4; ++i)
#pragma unroll
        for (int j = 0; j < 2; ++j)
#pragma unroll
            for (int e = 0; e < 4; ++e) {
                int row = mtile + wm * 64 + i * 16 + q * 4 + e;
                int col = ntile + wn * 32 + j * 16 + r16;
                C[(size_t)row * C_ + col] = acc[i][j][e];
            }
}

// ---------------------------------------------------------------------------
// Fused stage-2 v2: dec=exp(w), kk (normalized), b = kk*a, k_final.
// t-tile 4 (grid 8x256 = 2048 blocks -> 8 blocks/CU). l2p partials
// [4][T][256]: cols 128-191 decay(tanh) | 192-207 aaa | 208-223 ma |
// 224-239 kkk(tanh) | 240-255 mk. Fixed-order reduce.
// ---------------------------------------------------------------------------
__global__ __launch_bounds__(256) void k_fuse(
    const float* __restrict__ l2p,
    float* __restrict__ K0,
    const float* __restrict__ decay_w2, const float* __restrict__ aaa_w2,
    const float* __restrict__ ma_w2, const float* __restrict__ kkk_w2,
    const float* __restrict__ mk_w2,
    const float* __restrict__ tdecay, const float* __restrict__ aaaaa,
    const float* __restrict__ misc_a, const float* __restrict__ misc_k,
    float* __restrict__ Dout, float* __restrict__ KKout, float* __restrict__ Bout)
{
    const int tid = threadIdx.x;
    const int c = blockIdx.x * 256 + tid;
    const int t0 = blockIdx.y * 4;
    const size_t P = (size_t)T_ * 256;
    __shared__ __align__(16) float wsS[4][96];   // decay64 | aaa16 | ma16
    __shared__ __align__(16) float ksS[4][32];   // kkk16 | mk16
    if (tid < 4 * 24) {
        int r = tid / 24, c4 = (tid % 24) * 4;
        size_t off = (size_t)(t0 + r) * 256 + 128 + c4;
        float4 v0 = *(const float4*)&l2p[off];
        float4 v1 = *(const float4*)&l2p[P + off];
        float4 v2 = *(const float4*)&l2p[2 * P + off];
        float4 v3 = *(const float4*)&l2p[3 * P + off];
        float4 v;
        v.x = ((v0.x + v1.x) + v2.x) + v3.x;
        v.y = ((v0.y + v1.y) + v2.y) + v3.y;
        v.z = ((v0.z + v1.z) + v2.z) + v3.z;
        v.w = ((v0.w + v1.w) + v2.w) + v3.w;
        if (c4 < 64) { v.x = tanhf(v.x); v.y = tanhf(v.y); v.z = tanhf(v.z); v.w = tanhf(v.w); }
        *(float4*)&wsS[r][c4] = v;
    }
    if (tid < 4 * 8) {
        int r = tid / 8, c4 = (tid % 8) * 4;
        size_t off = (size_t)(t0 + r) * 256 + 224 + c4;
        float4 v0 = *(const float4*)&l2p[off];
        float4 v1 = *(const float4*)&l2p[P + off];
        float4 v2 = *(const float4*)&l2p[2 * P + off];
        float4 v3 = *(const float4*)&l2p[3 * P + off];
        float4 v;
        v.x = ((v0.x + v1.x) + v2.x) + v3.x;
        v.y = ((v0.y + v1.y) + v2.y) + v3.y;
        v.z = ((v0.z + v1.z) + v2.z) + v3.z;
        v.w = ((v0.w + v1.w) + v2.w) + v3.w;
        if (c4 < 16) { v.x = tanhf(v.x); v.y = tanhf(v.y); v.z = tanhf(v.z); v.w = tanhf(v.w); }
        *(float4*)&ksS[r][c4] = v;
    }
    __syncthreads();
    float accW[4], accA[4], accMA[4], accKK[4], accMK[4];
#pragma unroll
    for (int r = 0; r < 4; ++r) { accW[r] = 0.f; accA[r] = 0.f; accMA[r] = 0.f; accKK[r] = 0.f; accMK[r] = 0.f; }
    for (int j = 0; j < 64; ++j) {
        float w = decay_w2[(size_t)j * C_ + c];
#pragma unroll
        for (int r = 0; r < 4; ++r) accW[r] = fmaf(wsS[r][j], w, accW[r]);
    }
    for (int j = 0; j < 16; ++j) {
        float wa = aaa_w2[(size_t)j * C_ + c];
        float wm = ma_w2[(size_t)j * C_ + c];
        float wk = kkk_w2[(size_t)j * C_ + c];
        float wq = mk_w2[(size_t)j * C_ + c];
#pragma unroll
        for (int r = 0; r < 4; ++r) {
            accA[r]  = fmaf(wsS[r][64 + j], wa, accA[r]);
            accMA[r] = fmaf(wsS[r][80 + j], wm, accMA[r]);
            accKK[r] = fmaf(ksS[r][j],      wk, accKK[r]);
            accMK[r] = fmaf(ksS[r][16 + j], wq, accMK[r]);
        }
    }
    float td = tdecay[c], aa = aaaaa[c], mia = misc_a[c], mik = misc_k[c];
#pragma unroll
    for (int r = 0; r < 4; ++r) {
        size_t idx = (size_t)(t0 + r) * C_ + c;
        float wraw = td + accW[r];
        float w = -__logf(1.0f + __expf(-wraw)) - 0.5f;   // -softplus(-x) - 0.5
        float a  = 1.0f / (1.0f + __expf(-(aa  + accA[r])));
        float mav = 1.0f / (1.0f + __expf(-(mia + accMA[r])));
        float mkv = 1.0f / (1.0f + __expf(-(mik + accMK[r])));
        float k0 = K0[idx];
        float kkun = k0 + accKK[r];
        float ss = kkun * kkun;
        REDUCE16(ss);
        ss += __shfl_xor(ss, 16, 64);
        ss += __shfl_xor(ss, 32, 64);
        float kn = kkun * (1.0f / fmaxf(sqrtf(ss), 1e-12f));
        Dout[idx]  = __expf(w);                 // dec, precomputed for the scan
        KKout[idx] = kn;
        Bout[idx]  = kn * a;
        K0[idx]    = k0 * (mav + a * (1.0f - mav)) * __expf(fminf(w * mkv, 0.0f));
    }
}

// ---------------------------------------------------------------------------
// WKV7 segmented scan, pass 1 (merged S+P). Grid (7 segs, 32 heads), 512 thr.
// Waves 0-3: S rows (init 0, +v k^T source). Waves 4-7: P rows (init I, no
// source -> vv=0). Each lane carries 4 ROW-STATES (rows row0..row0+3, j-window
// j4..j4+3); per-step d/a/b (+k/v) LDS reads shared by 16 rows per wave.
// ---------------------------------------------------------------------------
__global__ __launch_bounds__(512) void k_wkv_p1(
    const float* __restrict__ DEC, const float* __restrict__ K,
    const float* __restrict__ V, const float* __restrict__ KK,
    const float* __restrict__ Bb,
    float* __restrict__ Send, float* __restrict__ Pend)
{
    const int tid = threadIdx.x;
    const int g = blockIdx.x;                  // segment 0..6
    const int h = blockIdx.y;                  // head
    const int c0 = h * 64;
    const int wv = tid >> 6, lane = tid & 63;
    const int jg = lane & 15, q = lane >> 4, j4 = jg * 4;
    const bool isS = wv < 4;
    const int row0 = (isS ? wv : wv - 4) * 16 + q * 4;   // rows row0..row0+3

    __shared__ __align__(16) float dS[2][16][64], kS[2][16][64], vS[2][16][64],
                                   aS[2][16][64], bS[2][16][64];

    // staging: pos in [0,256) covers one 4KB array-chunk; grp picks arrays.
    // per-wave lds dest = wave-uniform base + lane*16 (DMA constraint holds).
    const int pos = tid & 255, grp = tid >> 8;
    const int pst = pos >> 4, pq4 = (pos & 15) * 4;

#define P1_STAGE(buf, tcb) do {                                               \
    size_t gg = (size_t)((tcb) + pst) * C_ + c0 + pq4;                        \
    if (grp == 0) { async_cp16(&DEC[gg], &dS[buf][pst][pq4]);                 \
                    async_cp16(&KK[gg],  &aS[buf][pst][pq4]);                 \
                    async_cp16(&Bb[gg],  &bS[buf][pst][pq4]); }               \
    else          { async_cp16(&K[gg], &kS[buf][pst][pq4]);                   \
                    async_cp16(&V[gg], &vS[buf][pst][pq4]); }                 \
} while (0)

    float4 s0, s1, s2, s3;
    if (isS) {
        s0 = make_float4(0.f, 0.f, 0.f, 0.f); s1 = s0; s2 = s0; s3 = s0;
    } else {
#define IDROW(m) make_float4((j4 + 0 == row0 + (m)) ? 1.f : 0.f,              \
                             (j4 + 1 == row0 + (m)) ? 1.f : 0.f,              \
                             (j4 + 2 == row0 + (m)) ? 1.f : 0.f,              \
                             (j4 + 3 == row0 + (m)) ? 1.f : 0.f)
        s0 = IDROW(0); s1 = IDROW(1); s2 = IDROW(2); s3 = IDROW(3);
#undef IDROW
    }

    const int t0 = g * 128;
    P1_STAGE(0, t0);

    for (int tc = 0; tc < 128; tc += 16) {
        const int p = (tc >> 4) & 1;
        __syncthreads();                               // buf p ready
        if (tc + 16 < 128) P1_STAGE(p ^ 1, t0 + tc + 16);
#pragma unroll
        for (int tt = 0; tt < 16; ++tt) {
            float4 cd = *(float4*)&dS[p][tt][j4];
            float4 ca = *(float4*)&aS[p][tt][j4];
            float4 cb = *(float4*)&bS[p][tt][j4];
            float4 ck, vv;
            if (isS) {                                 // wave-uniform branch
                ck = *(float4*)&kS[p][tt][j4];
                vv = *(float4*)&vS[p][tt][row0];       // v for rows row0..+3
            } else {
                ck = make_float4(0.f, 0.f, 0.f, 0.f);
                vv = make_float4(0.f, 0.f, 0.f, 0.f);
            }
            float sa0 = -(fmaf(s0.y, ca.y, s0.x * ca.x) + fmaf(s0.w, ca.w, s0.z * ca.z));
            float sa1 = -(fmaf(s1.y, ca.y, s1.x * ca.x) + fmaf(s1.w, ca.w, s1.z * ca.z));
            float sa2 = -(fmaf(s2.y, ca.y, s2.x * ca.x) + fmaf(s2.w, ca.w, s2.z * ca.z));
            float sa3 = -(fmaf(s3.y, ca.y, s3.x * ca.x) + fmaf(s3.w, ca.w, s3.z * ca.z));
            REDUCE16(sa0); REDUCE16(sa1); REDUCE16(sa2); REDUCE16(sa3);
            s0.x = fmaf(s0.x, cd.x, fmaf(sa0, cb.x, vv.x * ck.x));
            s0.y = fmaf(s0.y, cd.y, fmaf(sa0, cb.y, vv.x * ck.y));
            s0.z = fmaf(s0.z, cd.z, fmaf(sa0, cb.z, vv.x * ck.z));
            s0.w = fmaf(s0.w, cd.w, fmaf(sa0, cb.w, vv.x * ck.w));
            s1.x = fmaf(s1.x, cd.x, fmaf(sa1, cb.x, vv.y * ck.x));
            s1.y = fmaf(s1.y, cd.y, fmaf(sa1, cb.y, vv.y * ck.y));
            s1.z = fmaf(s1.z, cd.z, fmaf(sa1, cb.z, vv.y * ck.z));
            s1.w = fmaf(s1.w, cd.w, fmaf(sa1, cb.w, vv.y * ck.w));
            s2.x = fmaf(s2.x, cd.x, fmaf(sa2, cb.x, vv.z * ck.x));
            s2.y = fmaf(s2.y, cd.y, fmaf(sa2, cb.y, vv.z * ck.y));
            s2.z = fmaf(s2.z, cd.z, fmaf(sa2, cb.z, vv.z * ck.z));
            s2.w = fmaf(s2.w, cd.w, fmaf(sa2, cb.w, vv.z * ck.w));
            s3.x = fmaf(s3.x, cd.x, fmaf(sa3, cb.x, vv.w * ck.x));
            s3.y = fmaf(s3.y, cd.y, fmaf(sa3, cb.y, vv.w * ck.y));
            s3.z = fmaf(s3.z, cd.z, fmaf(sa3, cb.z, vv.w * ck.z));
            s3.w = fmaf(s3.w, cd.w, fmaf(sa3, cb.w, vv.w * ck.w));
        }
    }
    float* dst = isS ? Send : Pend;
    size_t base = (size_t)((h * 7 + g) * 64 + row0) * 64 + j4;
    *(float4*)&dst[base +   0] = s0;
    *(float4*)&dst[base +  64] = s1;
    *(float4*)&dst[base + 128] = s2;
    *(float4*)&dst[base + 192] = s3;
#undef P1_STAGE
}

// ---------------------------------------------------------------------------
// WKV7 segmented scan, combine. 32 blocks (1/head) x 256 thr.
// Sin(h,0) = 0; Sin(h,g) = Sin(h,g-1) @ P(h,g-1) + Send(h,g-1), g=1..7.
// Thread t: row i = t>>2, cols jq..jq+15 where jq = (t&3)*16.
// ---------------------------------------------------------------------------
__global__ __launch_bounds__(256) void k_wkv_comb(
    const float* __restrict__ Send, const float* __restrict__ Pend,
    float* __restrict__ Sin)
{
    const int h = blockIdx.x;
    const int tid = threadIdx.x;
    const int i = tid >> 2;
    const int jq = (tid & 3) * 16;
    __shared__ float Sc[64][65];               // padded: Sc[i][k] conflict-free
    __shared__ __align__(16) float Pl[64][64];

    float4 z4 = make_float4(0.f, 0.f, 0.f, 0.f);
#pragma unroll
    for (int c = 0; c < 16; c += 4)
        *(float4*)&Sin[(size_t)(h * 8) * 4096 + (size_t)i * 64 + jq + c] = z4;
#pragma unroll
    for (int c = 0; c < 16; ++c) Sc[i][jq + c] = 0.f;
    __syncthreads();

    for (int g = 1; g < 8; ++g) {
        const float* Pg = &Pend[(size_t)(h * 7 + g - 1) * 4096];
        for (int idx = tid * 4; idx < 4096; idx += 1024) {
            float4 v = *(const float4*)&Pg[idx];
            *(float4*)&Pl[idx >> 6][idx & 63] = v;
        }
        __syncthreads();
        float acc[16];
        const float* Sg = &Send[(size_t)(h * 7 + g - 1) * 4096 + (size_t)i * 64 + jq];
#pragma unroll
        for (int c = 0; c < 16; c += 4) {
            float4 v = *(const float4*)&Sg[c];
            acc[c] = v.x; acc[c + 1] = v.y; acc[c + 2] = v.z; acc[c + 3] = v.w;
        }
        for (int k = 0; k < 64; ++k) {
            float sik = Sc[i][k];
#pragma unroll
            for (int c = 0; c < 16; ++c) acc[c] = fmaf(sik, Pl[k][jq + c], acc[c]);
        }
        __syncthreads();                       // all reads of Sc/Pl done
        float* So = &Sin[(size_t)(h * 8 + g) * 4096 + (size_t)i * 64 + jq];
#pragma unroll
        for (int c = 0; c < 16; ++c) Sc[i][jq + c] = acc[c];
#pragma unroll
        for (int c = 0; c < 16; c += 4) {
            float4 v = make_float4(acc[c], acc[c + 1], acc[c + 2], acc[c + 3]);
            *(float4*)&So[c] = v;
        }
        __syncthreads();                       // Sc updated for next g
    }
}

// ---------------------------------------------------------------------------
// WKV7 segmented scan, pass 2. Grid (8 segs, 32 heads), 256 thr (4 waves x
// 16 rows; 4 row-states per lane). Replay from exact Sin(h,g), emit Y as
// float4 (rows row0..row0+3). Output reductions deferred per 8-step half.
// ---------------------------------------------------------------------------
__global__ __launch_bounds__(256) void k_wkv_p2(
    const float* __restrict__ R, const float* __restrict__ DEC,
    const float* __restrict__ K, const float* __restrict__ V,
    const float* __restrict__ KK, const float* __restrict__ Bb,
    const float* __restrict__ Sin, float* __restrict__ Y)
{
    const int tid = threadIdx.x;
    const int g = blockIdx.x;                  // segment 0..7
    const int h = blockIdx.y;
    const int c0 = h * 64;
    const int wv = tid >> 6, lane = tid & 63;
    const int jg = lane & 15, q = lane >> 4, j4 = jg * 4;
    const int row0 = wv * 16 + q * 4;          // rows row0..row0+3

    __shared__ __align__(16) float rS[2][16][64], dS[2][16][64], kS[2][16][64],
                                   aS[2][16][64], bS[2][16][64], vS[2][16][64];

    const int pst = tid >> 4, pq4 = (tid & 15) * 4;

#define P2_STAGE(buf, tcb) do {                                               \
    size_t gg = (size_t)((tcb) + pst) * C_ + c0 + pq4;                        \
    async_cp16(&R[gg],   &rS[buf][pst][pq4]);                                 \
    async_cp16(&DEC[gg], &dS[buf][pst][pq4]);                                 \
    async_cp16(&K[gg],   &kS[buf][pst][pq4]);                                 \
    async_cp16(&V[gg],   &vS[buf][pst][pq4]);                                 \
    async_cp16(&KK[gg],  &aS[buf][pst][pq4]);                                 \
    async_cp16(&Bb[gg],  &bS[buf][pst][pq4]);                                 \
} while (0)

    float4 s0, s1, s2, s3;
    {
        const float* Sb = &Sin[(size_t)((h * 8 + g) * 64 + row0) * 64 + j4];
        s0 = *(const float4*)&Sb[0];
        s1 = *(const float4*)&Sb[64];
        s2 = *(const float4*)&Sb[128];
        s3 = *(const float4*)&Sb[192];
    }

    const int t0 = g * 128;
    P2_STAGE(0, t0);

    for (int tc = 0; tc < 128; tc += 16) {
        const int p = (tc >> 4) & 1;
        __syncthreads();                               // buf p ready
        if (tc + 16 < 128) P2_STAGE(p ^ 1, t0 + tc + 16);
#pragma unroll
        for (int hh = 0; hh < 2; ++hh) {
            float po0[8], po1[8], po2[8], po3[8];
#pragma unroll
            for (int qs2 = 0; qs2 < 8; ++qs2) {
                const int tt = hh * 8 + qs2;
                float4 cr = *(float4*)&rS[p][tt][j4];
                float4 cd = *(float4*)&dS[p][tt][j4];
                float4 ck = *(float4*)&kS[p][tt][j4];
                float4 ca = *(float4*)&aS[p][tt][j4];
                float4 cb = *(float4*)&bS[p][tt][j4];
                float4 vv = *(float4*)&vS[p][tt][row0];
                float sa0 = -(fmaf(s0.y, ca.y, s0.x * ca.x) + fmaf(s0.w, ca.w, s0.z * ca.z));
                float sa1 = -(fmaf(s1.y, ca.y, s1.x * ca.x) + fmaf(s1.w, ca.w, s1.z * ca.z));
                float sa2 = -(fmaf(s2.y, ca.y, s2.x * ca.x) + fmaf(s2.w, ca.w, s2.z * ca.z));
                float sa3 = -(fmaf(s3.y, ca.y, s3.x * ca.x) + fmaf(s3.w, ca.w, s3.z * ca.z));
                REDUCE16(sa0); REDUCE16(sa1); REDUCE16(sa2); REDUCE16(sa3);
                s0.x = fmaf(s0.x, cd.x, fmaf(sa0, cb.x, vv.x * ck.x));
                s0.y = fmaf(s0.y, cd.y, fmaf(sa0, cb.y, vv.x * ck.y));
                s0.z = fmaf(s0.z, cd.z, fmaf(sa0, cb.z, vv.x * ck.z));
                s0.w = fmaf(s0.w, cd.w, fmaf(sa0, cb.w, vv.x * ck.w));
                s1.x = fmaf(s1.x, cd.x, fmaf(sa1, cb.x, vv.y * ck.x));
                s1.y = fmaf(s1.y, cd.y, fmaf(sa1, cb.y, vv.y * ck.y));
                s1.z = fmaf(s1.z, cd.z, fmaf(sa1, cb.z, vv.y * ck.z));
                s1.w = fmaf(s1.w, cd.w, fmaf(sa1, cb.w, vv.y * ck.w));
                s2.x = fmaf(s2.x, cd.x, fmaf(sa2, cb.x, vv.z * ck.x));
                s2.y = fmaf(s2.y, cd.y, fmaf(sa2, cb.y, vv.z * ck.y));
                s2.z = fmaf(s2.z, cd.z, fmaf(sa2, cb.z, vv.z * ck.z));
                s2.w = fmaf(s2.w, cd.w, fmaf(sa2, cb.w, vv.z * ck.w));
                s3.x = fmaf(s3.x, cd.x, fmaf(sa3, cb.x, vv.w * ck.x));
                s3.y = fmaf(s3.y, cd.y, fmaf(sa3, cb.y, vv.w * ck.y));
                s3.z = fmaf(s3.z, cd.z, fmaf(sa3, cb.z, vv.w * ck.z));
                s3.w = fmaf(s3.w, cd.w, fmaf(sa3, cb.w, vv.w * ck.w));
                po0[qs2] = fmaf(s0.w, cr.w, fmaf(s0.z, cr.z, fmaf(s0.y, cr.y, s0.x * cr.x)));
                po1[qs2] = fmaf(s1.w, cr.w, fmaf(s1.z, cr.z, fmaf(s1.y, cr.y, s1.x * cr.x)));
                po2[qs2] = fmaf(s2.w, cr.w, fmaf(s2.z, cr.z, fmaf(s2.y, cr.y, s2.x * cr.x)));
                po3[qs2] = fmaf(s3.w, cr.w, fmaf(s3.z, cr.z, fmaf(s3.y, cr.y, s3.x * cr.x)));
            }
            // deferred: 32 independent DPP butterflies pipeline
#pragma unroll
            for (int qs2 = 0; qs2 < 8; ++qs2) {
                REDUCE16(po0[qs2]); REDUCE16(po1[qs2]);
                REDUCE16(po2[qs2]); REDUCE16(po3[qs2]);
            }
            if (jg == 0) {
#pragma unroll
                for (int qs2 = 0; qs2 < 8; ++qs2) {
                    float4 o = make_float4(po0[qs2], po1[qs2], po2[qs2], po3[qs2]);
                    *(float4*)&Y[(size_t)(t0 + tc + hh * 8 + qs2) * C_ + c0 + row0] = o;
                }
            }
        }
    }
#undef P2_STAGE
}

// ---------------------------------------------------------------------------
// GroupNorm + bonus + fused gate, t-tiled (16 t/block so the 128 gw2 loads
// amortize): YG = f16((gn(y) + bonus) * (tanh(l2 sum) @ gate_w2)).
// ---------------------------------------------------------------------------
__global__ __launch_bounds__(256) void k_gn(
    const float* __restrict__ Y, const float* __restrict__ R, const float* __restrict__ K,
    const float* __restrict__ V, const float* __restrict__ l2p,
    const float* __restrict__ gw2,
    const float* __restrict__ faaaa, const float* __restrict__ lnw,
    const float* __restrict__ lnb, _Float16* __restrict__ YG)
{
    const int tid = threadIdx.x;
    const int c = blockIdx.x * 256 + tid;
    const int t0 = blockIdx.y * 16;
    const size_t P = (size_t)T_ * 256;
    __shared__ __align__(16) float gs[16][128];
    for (int id = tid; id < 16 * 128; id += 256) {
        int r = id >> 7, cc = id & 127;
        size_t off = (size_t)(t0 + r) * 256 + cc;
        float v = ((l2p[off] + l2p[P + off]) + l2p[2 * P + off]) + l2p[3 * P + off];
        gs[r][cc] = tanhf(v);
    }
    __syncthreads();
    float gacc[16];
#pragma unroll
    for (int r = 0; r < 16; ++r) gacc[r] = 0.f;
    for (int j = 0; j < 128; ++j) {
        float w = gw2[(size_t)j * C_ + c];
#pragma unroll
        for (int r = 0; r < 16; ++r) gacc[r] = fmaf(gs[r][j], w, gacc[r]);
    }
    float fa = faaaa[c], lw = lnw[c], lb = lnb[c];
    for (int r = 0; r < 16; ++r) {
        const size_t idx = (size_t)(t0 + r) * C_ + c;
        float y = Y[idx];
        float s1 = y, s2 = y * y;
#pragma unroll
        for (int off = 1; off < 64; off <<= 1) {
            s1 += __shfl_xor(s1, off, 64);
            s2 += __shfl_xor(s2, off, 64);
        }
        float mu = s1 * (1.0f / 64.0f);
        float var = s2 * (1.0f / 64.0f) - mu * mu;
        float gn = (y - mu) * rsqrtf(var + 0.00064f) * lw + lb;
        float p = R[idx] * K[idx] * fa;
#pragma unroll
        for (int off = 1; off < 64; off <<= 1) p += __shfl_xor(p, off, 64);
        float y2 = gn + p * V[idx];
        YG[idx] = (_Float16)(y2 * gacc[r]);
    }
}

// ---------------------------------------------------------------------------
extern "C" void kernel_launch(void* const* d_in, const int* in_sizes, int n_in,
                              void* d_out, int out_size, void* d_ws, size_t ws_size,
                              hipStream_t stream)
{
    (void)in_sizes; (void)n_in; (void)out_size; (void)ws_size;
    const float* hidden   = (const float*)d_in[0];
    const float* Wq       = (const float*)d_in[1];
    const float* Wk       = (const float*)d_in[2];
    const float* Wv       = (const float*)d_in[3];
    const float* Wo       = (const float*)d_in[4];
    const float* maa_x    = (const float*)d_in[5];
    const float* maa_rg   = (const float*)d_in[6];
    const float* maa_wa   = (const float*)d_in[7];
    const float* maa_k    = (const float*)d_in[8];
    const float* maa_v    = (const float*)d_in[9];
    const float* maa_w1   = (const float*)d_in[10];
    const float* maa_w2   = (const float*)d_in[11];
    const float* tdecay   = (const float*)d_in[12];
    const float* decay_w1 = (const float*)d_in[13];
    const float* decay_w2 = (const float*)d_in[14];
    const float* aaaaa    = (const float*)d_in[15];
    const float* aaa_w1   = (const float*)d_in[16];
    const float* aaa_w2   = (const float*)d_in[17];
    const float* kkk_w1   = (const float*)d_in[18];
    const float* kkk_w2   = (const float*)d_in[19];
    const float* gate_w1  = (const float*)d_in[20];
    const float* gate_w2  = (const float*)d_in[21];
    const float* misc_a   = (const float*)d_in[22];
    const float* ma_w1    = (const float*)d_in[23];
    const float* ma_w2    = (const float*)d_in[24];
    const float* misc_k   = (const float*)d_in[25];
    const float* mk_w1    = (const float*)d_in[26];
    const float* mk_w2    = (const float*)d_in[27];
    const float* faaaa    = (const float*)d_in[28];
    const float* lnw      = (const float*)d_in[29];
    const float* lnb      = (const float*)d_in[30];

    float* ws = (float*)d_ws;
    const size_t TC = (size_t)T_ * C_;
    // f32 buffers:
    //   S0: y   S2: b   S3: kk   S4: r   S5: dec   S6: k0 -> k   S7: v
    //   S1 slot (8MB) repurposed: Send [32][7][64][64] + Pend [32][7][64][64]
    float* S0 = ws + 0 * TC;
    float* Send = ws + 1 * TC;                   // 917504 floats
    float* Pend = Send + (size_t)32 * 7 * 64 * 64;
    float* S2 = ws + 2 * TC;
    float* S3 = ws + 3 * TC;
    float* S4 = ws + 4 * TC;
    float* S5 = ws + 5 * TC;
    float* S6 = ws + 6 * TC;
    float* S7 = ws + 7 * TC;
    float* m1p = ws + 8 * TC;                    // [4][T][128] partials
    float* l2p = m1p + (size_t)4 * T_ * 128;     // [4][T][256] partials
    // f16 region
    _Float16* WTq = (_Float16*)(l2p + (size_t)4 * T_ * 256);
    _Float16* WTk = WTq + (size_t)C_ * C_;
    _Float16* WTv = WTk + (size_t)C_ * C_;
    _Float16* WTo = WTv + (size_t)C_ * C_;
    _Float16* WTm = WTo + (size_t)C_ * C_;       // [128,2048]
    _Float16* WTl = WTm + (size_t)128 * C_;      // [256,2048]
    _Float16* xxxH = WTl + (size_t)256 * C_;
    _Float16* xrgH = xxxH + TC;
    _Float16* xwaH = xrgH + TC;
    _Float16* xkH  = xwaH + TC;
    _Float16* xvH  = xkH + TC;
    _Float16* ygH  = xxxH;                       // xxxH dead after step 6
    // xrgH dead after step 7 -> reuse its 4MB as Sin [32][8][64][64] f32
    float* Sin = (float*)xrgH;
    float* out = (float*)d_out;

    // 1. transpose+convert big weights
    k_tr<<<dim3(32, 32, 4), 256, 0, stream>>>(Wq, Wk, Wv, Wo, WTq, WTk, WTv, WTo);
    // 2. pack+transpose LoRA weights (z=0: WTm, z=1: WTl)
    k_trW<<<dim3(8, 256, 2), 256, 0, stream>>>(maa_w1, gate_w1, decay_w1,
        aaa_w1, ma_w1, kkk_w1, mk_w1, WTm, WTl);
    // 3. xxxH
    k_prep<<<dim3((int)(TC / 256)), 256, 0, stream>>>(hidden, maa_x, xxxH);
    // 4. m1 partials = xxxH @ WTm^T
    k_lora<<<dim3(16, 4, 4), 256, 0, stream>>>(0, xxxH, xxxH, xxxH, xxxH,
        WTm, WTl, m1p, l2p);
    // 5. xmix -> f16 operands
    k_xmix<<<dim3(8, 64), 256, 0, stream>>>(hidden, m1p, maa_w2,
        maa_rg, maa_wa, maa_k, maa_v, xrgH, xwaH, xkH, xvH);
    // 6. l2 partials (gate | decay | aaa | ma | kkk | mk)
    k_lora<<<dim3(16, 8, 4), 256, 0, stream>>>(1, xxxH, xrgH, xwaH, xkH,
        WTm, WTl, m1p, l2p);
    // 7. r, k0, v (f16 MFMA, BN=64: 768 blocks)
    k_gemm<<<dim3(32, 8, 3), 256, 0, stream>>>(
        xrgH, WTq, S4,  xkH, WTk, S6,  xvH, WTv, S7);
    // 8. fused stage-2: dec, kk (normalized), b, k_final (t-tile 4)
    k_fuse<<<dim3(8, 256), 256, 0, stream>>>(l2p, S6, decay_w2, aaa_w2, ma_w2,
        kkk_w2, mk_w2, tdecay, aaaaa, misc_a, misc_k, S5, S3, S2);
    // 9. WKV7 segmented scan (8 segments of 128 steps):
    //    9a. pass 1 (merged): local end-states + transition products
    k_wkv_p1<<<dim3(7, 32), 512, 0, stream>>>(S5, S6, S7, S3, S2, Send, Pend);
    //    9b. combine: Sin(g) = Sin(g-1) @ P(g-1) + Send(g-1)
    k_wkv_comb<<<dim3(32), 256, 0, stream>>>(Send, Pend, Sin);
    //    9c. pass 2: replay segments from exact Sin, emit Y
    k_wkv_p2<<<dim3(8, 32), 256, 0, stream>>>(S4, S5, S6, S7, S3, S2, Sin, S0);
    // 10. groupnorm + bonus + fused gate -> f16 (reuses xxxH slot)
    k_gn<<<dim3(8, 64), 256, 0, stream>>>(S0, S4, S6, S7, l2p, gate_w2,
        faaaa, lnw, lnb, ygH);
    // 11. out = (y*g) @ Wo (BN=64: 256 blocks)
    k_gemm<<<dim3(32, 8, 1), 256, 0, stream>>>(
        ygH, WTo, out,  ygH, WTo, out,  ygH, WTo, out);
}